// Round 1
// baseline (347.455 us; speedup 1.0000x reference)
//
#include <hip/hip_runtime.h>
#include <stdint.h>

#define NB 16
#define NH 8
#define LQ 1024
#define LKV 1424
#define LKVP 1472
#define DIMC 384
#define NKVT 23
#define SCALE_F 0.14433756729740643f  // 1/sqrt(48)

typedef __attribute__((ext_vector_type(4))) float f32x4;
typedef __attribute__((ext_vector_type(8))) short bf16x8;
typedef __attribute__((ext_vector_type(4))) unsigned short us4;
typedef __attribute__((ext_vector_type(4))) unsigned int u32x4;

__device__ __forceinline__ unsigned short f2b(float f) {
  unsigned int u = __builtin_bit_cast(unsigned int, f);
  u += 0x7fffu + ((u >> 16) & 1u);  // round-to-nearest-even
  return (unsigned short)(u >> 16);
}

__device__ __forceinline__ void gload_lds16(const void* gsrc, void* ldst) {
  __builtin_amdgcn_global_load_lds(
      (const __attribute__((address_space(1))) void*)gsrc,
      (__attribute__((address_space(3))) void*)ldst, 16, 0, 0);
}

// ---------------- init: zero Qp/Kp/Vt (pads must be 0) ----------------
__global__ __launch_bounds__(256) void init_ws(u32x4* p, int n) {
  int i = blockIdx.x * 256 + threadIdx.x;
  if (i < n) { u32x4 z = {0u, 0u, 0u, 0u}; p[i] = z; }
}

// ---------------- projection GEMMs ----------------
// C[m][n] = A[m][:] . W[n][:] + bias[n], bf16 MFMA, f32 acc.
// MODE 0: A=q f32 (16384x384), N=384 -> Qp (B*H,Lq,64) padded, *SCALE
// MODE 1: A=kv f32 (22784x384), N=768 -> Kp swizzled (B*H,LKVP,64) / Vt (B*H,48,LKVP) + mask
// MODE 2: A=X bf16 (16384x384), N=384 -> out f32
template <int MODE>
__global__ __launch_bounds__(256) void proj_gemm(
    const float* __restrict__ Af, const unsigned short* __restrict__ Ab,
    const float* __restrict__ W, const float* __restrict__ bias,
    const float* __restrict__ tem, const float* __restrict__ srch,
    unsigned short* __restrict__ Oq, unsigned short* __restrict__ Ok,
    unsigned short* __restrict__ Ovt, float* __restrict__ Of) {
  __shared__ unsigned short Ash[64 * 64];
  __shared__ unsigned short Bsh[64 * 64];
  const int tid = threadIdx.x;
  const int lane = tid & 63, l16 = lane & 15, g = lane >> 4;
  const int wave = tid >> 6, wm = wave >> 1, wn = wave & 1;
  const int n0 = blockIdx.x * 64, m0 = blockIdx.y * 64;

  f32x4 acc[2][2];
#pragma unroll
  for (int i = 0; i < 2; ++i)
#pragma unroll
    for (int j = 0; j < 2; ++j) { f32x4 z = {0.f, 0.f, 0.f, 0.f}; acc[i][j] = z; }

  for (int ks = 0; ks < 6; ++ks) {
    const int k0 = ks * 64;
    __syncthreads();
    if (MODE == 2) {
#pragma unroll
      for (int j = 0; j < 2; ++j) {
        int idx = tid + j * 256;
        int row = idx >> 3, c8 = idx & 7;
        bf16x8 v = *(const bf16x8*)(Ab + (size_t)(m0 + row) * DIMC + k0 + c8 * 8);
        *(bf16x8*)((char*)Ash + row * 128 + ((c8 ^ (row & 7)) << 4)) = v;
      }
    } else {
#pragma unroll
      for (int j = 0; j < 4; ++j) {
        int idx = tid + j * 256;
        int row = idx >> 4, c4 = idx & 15;
        f32x4 v = *(const f32x4*)(Af + (size_t)(m0 + row) * DIMC + k0 + c4 * 4);
        us4 u = {f2b(v[0]), f2b(v[1]), f2b(v[2]), f2b(v[3])};
        *(us4*)((char*)Ash + row * 128 + (((c4 >> 1) ^ (row & 7)) << 4) + (c4 & 1) * 8) = u;
      }
    }
#pragma unroll
    for (int j = 0; j < 4; ++j) {
      int idx = tid + j * 256;
      int row = idx >> 4, c4 = idx & 15;
      f32x4 v = *(const f32x4*)(W + (size_t)(n0 + row) * DIMC + k0 + c4 * 4);
      us4 u = {f2b(v[0]), f2b(v[1]), f2b(v[2]), f2b(v[3])};
      *(us4*)((char*)Bsh + row * 128 + (((c4 >> 1) ^ (row & 7)) << 4) + (c4 & 1) * 8) = u;
    }
    __syncthreads();
#pragma unroll
    for (int kk = 0; kk < 2; ++kk) {
      bf16x8 a[2], bb[2];
#pragma unroll
      for (int mi = 0; mi < 2; ++mi) {
        int row = wm * 32 + mi * 16 + l16;
        a[mi] = *(const bf16x8*)((char*)Ash + row * 128 + (((g + 4 * kk) ^ (row & 7)) << 4));
      }
#pragma unroll
      for (int ni = 0; ni < 2; ++ni) {
        int row = wn * 32 + ni * 16 + l16;
        bb[ni] = *(const bf16x8*)((char*)Bsh + row * 128 + (((g + 4 * kk) ^ (row & 7)) << 4));
      }
#pragma unroll
      for (int mi = 0; mi < 2; ++mi)
#pragma unroll
        for (int ni = 0; ni < 2; ++ni)
          acc[mi][ni] = __builtin_amdgcn_mfma_f32_16x16x32_bf16(a[mi], bb[ni], acc[mi][ni], 0, 0, 0);
    }
  }

#pragma unroll
  for (int mi = 0; mi < 2; ++mi) {
#pragma unroll
    for (int ni = 0; ni < 2; ++ni) {
      const int n_g = n0 + wn * 32 + ni * 16 + l16;
      const float bv = bias[n_g];
#pragma unroll
      for (int r = 0; r < 4; ++r) {
        const int m_g = m0 + wm * 32 + mi * 16 + 4 * g + r;
        float v = acc[mi][ni][r] + bv;
        if (MODE == 0) {
          v *= SCALE_F;
          int b = m_g >> 10, m = m_g & 1023;
          int hh = n_g / 48, d = n_g - hh * 48;
          Oq[(((size_t)b * NH + hh) * LQ + m) * 64 + d] = f2b(v);
        } else if (MODE == 1) {
          int b = m_g / LKV, s = m_g - b * LKV;
          if (n_g < DIMC) {
            int hh = n_g / 48, d = n_g - hh * 48;
            int dsw = (d & 7) | (((d >> 3) ^ (s & 7)) << 3);  // pre-swizzle for LDS
            Ok[(((size_t)b * NH + hh) * LKVP + s) * 64 + dsw] = f2b(v);
          } else {
            int c = n_g - DIMC;
            float msk = (s < 400) ? tem[((size_t)b * 400 + s) * DIMC + c]
                                  : srch[((size_t)b * 1024 + (s - 400)) * DIMC + c];
            int hh = c / 48, d = c - hh * 48;
            Ovt[(((size_t)b * NH + hh) * 48 + d) * LKVP + s] = f2b(v + msk);
          }
        } else {
          Of[(size_t)m_g * DIMC + n_g] = v;
        }
      }
    }
  }
}

// ---------------- flash attention ----------------
// grid (Lq/64, H, B), 256 thr = 4 waves x 16 q-rows. Q in regs (scale folded),
// K tile via global_load_lds (pre-swizzled), online softmax, P through per-wave
// swizzled LDS, V^T fragments straight from global (L2-resident).
__global__ __launch_bounds__(256) void attn_fwd(
    const float* __restrict__ pos, const unsigned short* __restrict__ Qp,
    const unsigned short* __restrict__ Kp, const unsigned short* __restrict__ Vt,
    unsigned short* __restrict__ X) {
  __shared__ unsigned short Ksh[64 * 64];
  __shared__ unsigned short Psh[4][16 * 64];

  const int tid = threadIdx.x;
  const int lane = tid & 63, l16 = lane & 15, g = lane >> 4;
  const int wave = tid >> 6;
  const int h = blockIdx.y, b = blockIdx.z;
  const int bh = b * NH + h;
  const int m0 = blockIdx.x * 64;
  const int qrow16 = m0 + wave * 16;

  bf16x8 qf[2];
  {
    const unsigned short* qb = Qp + ((size_t)bh * LQ + qrow16 + l16) * 64 + 8 * g;
    qf[0] = *(const bf16x8*)qb;
    qf[1] = *(const bf16x8*)(qb + 32);
  }

  float m_run[4], l_run[4];
  f32x4 o[3];
#pragma unroll
  for (int r = 0; r < 4; ++r) { m_run[r] = -1e30f; l_run[r] = 0.f; }
#pragma unroll
  for (int d = 0; d < 3; ++d) { f32x4 z = {0.f, 0.f, 0.f, 0.f}; o[d] = z; }

  const char* kp_base = (const char*)(Kp + (size_t)bh * LKVP * 64);
  unsigned short* pb = &Psh[wave][0];

  for (int t = 0; t < NKVT; ++t) {
    const int n0 = t * 64;
    {
      const char* src = kp_base + (size_t)n0 * 128 + wave * 2048 + lane * 16;
      char* dst = (char*)Ksh + wave * 2048;
      gload_lds16(src, dst);
      gload_lds16(src + 1024, dst + 1024);
    }
    asm volatile("s_waitcnt vmcnt(0)" ::: "memory");
    __syncthreads();

    f32x4 s[4];
#pragma unroll
    for (int ni = 0; ni < 4; ++ni) { f32x4 z = {0.f, 0.f, 0.f, 0.f}; s[ni] = z; }
#pragma unroll
    for (int ni = 0; ni < 4; ++ni) {
      const int krow = ni * 16 + l16;
#pragma unroll
      for (int kk = 0; kk < 2; ++kk) {
        bf16x8 kf = *(const bf16x8*)((const char*)Ksh + krow * 128 +
                                     (((g + 4 * kk) ^ (krow & 7)) << 4));
        s[ni] = __builtin_amdgcn_mfma_f32_16x16x32_bf16(qf[kk], kf, s[ni], 0, 0, 0);
      }
    }

    float p[4][4];
    const float* pr = pos + ((size_t)h * LQ + qrow16 + 4 * g) * LKV + n0 + l16;
#pragma unroll
    for (int ni = 0; ni < 4; ++ni) {
      const bool valid = (n0 + ni * 16) < LKV;  // uniform per fragment
#pragma unroll
      for (int r = 0; r < 4; ++r)
        p[ni][r] = valid ? (s[ni][r] + pr[(size_t)r * LKV + ni * 16]) : -1e30f;
    }

#pragma unroll
    for (int r = 0; r < 4; ++r) {
      float mx = fmaxf(fmaxf(p[0][r], p[1][r]), fmaxf(p[2][r], p[3][r]));
      mx = fmaxf(mx, __shfl_xor(mx, 1));
      mx = fmaxf(mx, __shfl_xor(mx, 2));
      mx = fmaxf(mx, __shfl_xor(mx, 4));
      mx = fmaxf(mx, __shfl_xor(mx, 8));
      const float mn = fmaxf(m_run[r], mx);
      const float al = __expf(m_run[r] - mn);
      float rs = 0.f;
#pragma unroll
      for (int ni = 0; ni < 4; ++ni) { float e = __expf(p[ni][r] - mn); p[ni][r] = e; rs += e; }
      rs += __shfl_xor(rs, 1);
      rs += __shfl_xor(rs, 2);
      rs += __shfl_xor(rs, 4);
      rs += __shfl_xor(rs, 8);
      l_run[r] = l_run[r] * al + rs;
      m_run[r] = mn;
      o[0][r] *= al; o[1][r] *= al; o[2][r] *= al;
    }

#pragma unroll
    for (int ni = 0; ni < 4; ++ni) {
      const int col = ni * 16 + l16;
#pragma unroll
      for (int r = 0; r < 4; ++r) {
        const int row = 4 * g + r;
        pb[row * 64 + (((col >> 3) ^ (row & 7)) << 3) + (col & 7)] = f2b(p[ni][r]);
      }
    }

    bf16x8 af[2];
#pragma unroll
    for (int kk = 0; kk < 2; ++kk)
      af[kk] = *(const bf16x8*)((const char*)pb + l16 * 128 +
                                (((g + 4 * kk) ^ (l16 & 7)) << 4));

    const unsigned short* vb = Vt + ((size_t)bh * 48 + l16) * LKVP + n0 + 8 * g;
#pragma unroll
    for (int dn = 0; dn < 3; ++dn) {
#pragma unroll
      for (int kk = 0; kk < 2; ++kk) {
        bf16x8 vf = *(const bf16x8*)(vb + (size_t)dn * 16 * LKVP + kk * 32);
        o[dn] = __builtin_amdgcn_mfma_f32_16x16x32_bf16(af[kk], vf, o[dn], 0, 0, 0);
      }
    }
    __syncthreads();
  }

#pragma unroll
  for (int r = 0; r < 4; ++r) {
    const float inv = 1.f / l_run[r];
    const int m = qrow16 + 4 * g + r;
    unsigned short* xp = X + ((size_t)b * LQ + m) * DIMC + h * 48 + l16;
    xp[0] = f2b(o[0][r] * inv);
    xp[16] = f2b(o[1][r] * inv);
    xp[32] = f2b(o[2][r] * inv);
  }
}

// ---------------- launch ----------------
extern "C" void kernel_launch(void* const* d_in, const int* in_sizes, int n_in,
                              void* d_out, int out_size, void* d_ws, size_t ws_size,
                              hipStream_t stream) {
  const float* tem  = (const float*)d_in[0];
  const float* srch = (const float*)d_in[1];
  const float* q    = (const float*)d_in[2];
  const float* kv   = (const float*)d_in[3];
  const float* pos  = (const float*)d_in[4];
  const float* q_w  = (const float*)d_in[5];
  const float* q_b  = (const float*)d_in[6];
  const float* kv_w = (const float*)d_in[7];
  const float* kv_b = (const float*)d_in[8];
  const float* p_w  = (const float*)d_in[9];
  const float* p_b  = (const float*)d_in[10];
  float* out = (float*)d_out;

  char* w = (char*)d_ws;
  unsigned short* Qp = (unsigned short*)(w);                        // 16 MB  (B*H,LQ,64)
  unsigned short* Kp = (unsigned short*)(w + 16777216);             // 23 MB  (B*H,LKVP,64) swz
  unsigned short* Vt = (unsigned short*)(w + 16777216 + 24117248);  // 17 MB  (B*H,48,LKVP)
  unsigned short* X  = (unsigned short*)(w + 58982400);             // 12 MB  (B*LQ,DIMC)

  init_ws<<<14400, 256, 0, stream>>>((u32x4*)w, 3686400);  // zero Qp+Kp+Vt (pads)
  proj_gemm<0><<<dim3(6, 256), 256, 0, stream>>>(q, nullptr, q_w, q_b, nullptr, nullptr,
                                                 Qp, nullptr, nullptr, nullptr);
  proj_gemm<1><<<dim3(12, 356), 256, 0, stream>>>(kv, nullptr, kv_w, kv_b, tem, srch,
                                                  nullptr, Kp, Vt, nullptr);
  attn_fwd<<<dim3(16, 8, 16), 256, 0, stream>>>(pos, Qp, Kp, Vt, X);
  proj_gemm<2><<<dim3(6, 256), 256, 0, stream>>>(nullptr, X, p_w, p_b, nullptr, nullptr,
                                                 nullptr, nullptr, nullptr, out);
}

// Round 2
// 344.655 us; speedup vs baseline: 1.0081x; 1.0081x over previous
//
#include <hip/hip_runtime.h>
#include <stdint.h>

#define NB 16
#define NH 8
#define LQ 1024
#define LKV 1424
#define LKVP 1472
#define DIMC 384
#define NKVT 23
#define QSCALE 0.20823509f       // (1/sqrt(48)) * log2(e)
#define LOG2E_F 1.4426950408889634f

typedef __attribute__((ext_vector_type(4))) float f32x4;
typedef __attribute__((ext_vector_type(8))) short bf16x8;
typedef __attribute__((ext_vector_type(4))) unsigned short us4;
typedef __attribute__((ext_vector_type(4))) unsigned int u32x4;

__device__ __forceinline__ unsigned short f2b(float f) {
  unsigned int u = __builtin_bit_cast(unsigned int, f);
  u += 0x7fffu + ((u >> 16) & 1u);  // round-to-nearest-even
  return (unsigned short)(u >> 16);
}
__device__ __forceinline__ float b2f(unsigned short u) {
  return __builtin_bit_cast(float, (unsigned int)u << 16);
}

__device__ __forceinline__ void gload_lds16(const void* gsrc, void* ldst) {
  __builtin_amdgcn_global_load_lds(
      (const __attribute__((address_space(1))) void*)gsrc,
      (__attribute__((address_space(3))) void*)ldst, 16, 0, 0);
}

// ---------------- init: zero Qp/Kp/Vt (pads must be 0, not poison) ----------------
__global__ __launch_bounds__(256) void init_ws(u32x4* p, int n) {
  int i = blockIdx.x * 256 + threadIdx.x;
  if (i < n) { u32x4 z = {0u, 0u, 0u, 0u}; p[i] = z; }
}

// ---------------- pos prep: f32 -> bf16, *log2e, fragment-ordered, padded ----------------
// out[((h*64+q16)*NKVT + t)*64 + lane]*16 + (ni*4+r)  where lane=g*16+l16,
// value = pos[h][q16*16+4g+r][t*64+ni*16+l16] * log2e  (cols >= LKV -> -1e30)
__global__ __launch_bounds__(256) void prep_pos(const float* __restrict__ pos,
                                                unsigned short* __restrict__ posb) {
  const int t = blockIdx.x, h = blockIdx.z;
  const int wave = threadIdx.x >> 6, lane = threadIdx.x & 63;
  const int q16 = blockIdx.y * 4 + wave;
  const int l16 = lane & 15, g = lane >> 4;
  unsigned short vals[16];
#pragma unroll
  for (int ni = 0; ni < 4; ++ni) {
    const int col = t * 64 + ni * 16 + l16;
#pragma unroll
    for (int r = 0; r < 4; ++r) {
      const int q = q16 * 16 + 4 * g + r;
      float v = (col < LKV) ? pos[((size_t)h * LQ + q) * LKV + col] * LOG2E_F : -1e30f;
      vals[ni * 4 + r] = f2b(v);
    }
  }
  unsigned short* op = posb + ((((size_t)h * 64 + q16) * NKVT + t) * 64 + lane) * 16;
  bf16x8 a, b;
#pragma unroll
  for (int i = 0; i < 8; ++i) { a[i] = (short)vals[i]; b[i] = (short)vals[8 + i]; }
  *(bf16x8*)op = a;
  *(bf16x8*)(op + 8) = b;
}

// ---------------- projection GEMMs ----------------
// MODE 0: A=q f32 -> Qp (B*H,Lq,64) padded, *QSCALE (scale+log2e folded)
// MODE 1: A=kv f32 -> Kp swizzled (B*H,LKVP,64) / Vt^T swizzled (B*H,48,LKVP) + mask
// MODE 2: A=X bf16 -> out f32
template <int MODE>
__global__ __launch_bounds__(256) void proj_gemm(
    const float* __restrict__ Af, const unsigned short* __restrict__ Ab,
    const float* __restrict__ W, const float* __restrict__ bias,
    const float* __restrict__ tem, const float* __restrict__ srch,
    unsigned short* __restrict__ Oq, unsigned short* __restrict__ Ok,
    unsigned short* __restrict__ Ovt, float* __restrict__ Of) {
  __shared__ unsigned short Ash[64 * 64];
  __shared__ unsigned short Bsh[64 * 64];
  const int tid = threadIdx.x;
  const int lane = tid & 63, l16 = lane & 15, g = lane >> 4;
  const int wave = tid >> 6, wm = wave >> 1, wn = wave & 1;
  const int n0 = blockIdx.x * 64, m0 = blockIdx.y * 64;

  f32x4 acc[2][2];
#pragma unroll
  for (int i = 0; i < 2; ++i)
#pragma unroll
    for (int j = 0; j < 2; ++j) { f32x4 z = {0.f, 0.f, 0.f, 0.f}; acc[i][j] = z; }

  for (int ks = 0; ks < 6; ++ks) {
    const int k0 = ks * 64;
    __syncthreads();
    if (MODE == 2) {
#pragma unroll
      for (int j = 0; j < 2; ++j) {
        int idx = tid + j * 256;
        int row = idx >> 3, c8 = idx & 7;
        bf16x8 v = *(const bf16x8*)(Ab + (size_t)(m0 + row) * DIMC + k0 + c8 * 8);
        *(bf16x8*)((char*)Ash + row * 128 + ((c8 ^ (row & 7)) << 4)) = v;
      }
    } else {
#pragma unroll
      for (int j = 0; j < 4; ++j) {
        int idx = tid + j * 256;
        int row = idx >> 4, c4 = idx & 15;
        f32x4 v = *(const f32x4*)(Af + (size_t)(m0 + row) * DIMC + k0 + c4 * 4);
        us4 u = {f2b(v[0]), f2b(v[1]), f2b(v[2]), f2b(v[3])};
        *(us4*)((char*)Ash + row * 128 + (((c4 >> 1) ^ (row & 7)) << 4) + (c4 & 1) * 8) = u;
      }
    }
#pragma unroll
    for (int j = 0; j < 4; ++j) {
      int idx = tid + j * 256;
      int row = idx >> 4, c4 = idx & 15;
      f32x4 v = *(const f32x4*)(W + (size_t)(n0 + row) * DIMC + k0 + c4 * 4);
      us4 u = {f2b(v[0]), f2b(v[1]), f2b(v[2]), f2b(v[3])};
      *(us4*)((char*)Bsh + row * 128 + (((c4 >> 1) ^ (row & 7)) << 4) + (c4 & 1) * 8) = u;
    }
    __syncthreads();
#pragma unroll
    for (int kk = 0; kk < 2; ++kk) {
      bf16x8 a[2], bb[2];
#pragma unroll
      for (int mi = 0; mi < 2; ++mi) {
        int row = wm * 32 + mi * 16 + l16;
        a[mi] = *(const bf16x8*)((char*)Ash + row * 128 + (((g + 4 * kk) ^ (row & 7)) << 4));
      }
#pragma unroll
      for (int ni = 0; ni < 2; ++ni) {
        int row = wn * 32 + ni * 16 + l16;
        bb[ni] = *(const bf16x8*)((char*)Bsh + row * 128 + (((g + 4 * kk) ^ (row & 7)) << 4));
      }
#pragma unroll
      for (int mi = 0; mi < 2; ++mi)
#pragma unroll
        for (int ni = 0; ni < 2; ++ni)
          acc[mi][ni] = __builtin_amdgcn_mfma_f32_16x16x32_bf16(a[mi], bb[ni], acc[mi][ni], 0, 0, 0);
    }
  }

#pragma unroll
  for (int mi = 0; mi < 2; ++mi) {
#pragma unroll
    for (int ni = 0; ni < 2; ++ni) {
      const int n_g = n0 + wn * 32 + ni * 16 + l16;
      const float bv = bias[n_g];
#pragma unroll
      for (int r = 0; r < 4; ++r) {
        const int m_g = m0 + wm * 32 + mi * 16 + 4 * g + r;
        float v = acc[mi][ni][r] + bv;
        if (MODE == 0) {
          v *= QSCALE;
          int b = m_g >> 10, m = m_g & 1023;
          int hh = n_g / 48, d = n_g - hh * 48;
          Oq[(((size_t)b * NH + hh) * LQ + m) * 64 + d] = f2b(v);
        } else if (MODE == 1) {
          int b = m_g / LKV, s = m_g - b * LKV;
          if (n_g < DIMC) {
            int hh = n_g / 48, d = n_g - hh * 48;
            int dsw = (d & 7) | (((d >> 3) ^ (s & 7)) << 3);  // pre-swizzle for LDS
            Ok[(((size_t)b * NH + hh) * LKVP + s) * 64 + dsw] = f2b(v);
          } else {
            int c = n_g - DIMC;
            float msk = (s < 400) ? tem[((size_t)b * 400 + s) * DIMC + c]
                                  : srch[((size_t)b * 1024 + (s - 400)) * DIMC + c];
            int hh = c / 48, d = c - hh * 48;
            int off = s & 63;  // pre-swizzle V^T row chunks for LDS
            int soff = (s & ~63) | ((((off >> 3) ^ d) & 7) << 3) | (off & 7);
            Ovt[(((size_t)b * NH + hh) * 48 + d) * LKVP + soff] = f2b(v + msk);
          }
        } else {
          Of[(size_t)m_g * DIMC + n_g] = v;
        }
      }
    }
  }
}

// ---------------- flash attention (double-buffered K+V in LDS, bf16 pos) ----------------
__device__ __forceinline__ void stage_tile(const char* kbase, const char* vbase, int t,
                                           char* kdst, char* vdst, int wave, int lane) {
  const char* ks = kbase + (size_t)t * 8192 + wave * 2048 + lane * 16;
  char* kd = kdst + wave * 2048;
  gload_lds16(ks, kd);
  gload_lds16(ks + 1024, kd + 1024);
  if (wave < 3) {  // V tile: 48 rows x 128B
    const char* vs = vbase + (size_t)(wave * 16 + (lane >> 3)) * (LKVP * 2) +
                     (size_t)t * 128 + (lane & 7) * 16;
    char* vd = vdst + wave * 2048;
    gload_lds16(vs, vd);
    gload_lds16(vs + 8 * (LKVP * 2), vd + 1024);
  }
}

__global__ __launch_bounds__(256) void attn_fwd(
    const unsigned short* __restrict__ posb, const unsigned short* __restrict__ Qp,
    const unsigned short* __restrict__ Kp, const unsigned short* __restrict__ Vt,
    unsigned short* __restrict__ X) {
  __shared__ unsigned short Ksh[2][64 * 64];
  __shared__ unsigned short Vsh[2][48 * 64];
  __shared__ unsigned short Psh[4][16 * 64];

  const int tid = threadIdx.x;
  const int lane = tid & 63, l16 = lane & 15, g = lane >> 4;
  const int wave = tid >> 6;
  const int h = blockIdx.y, b = blockIdx.z;
  const int bh = b * NH + h;
  const int m0 = blockIdx.x * 64;
  const int qrow16 = m0 + wave * 16;

  bf16x8 qf[2];
  {
    const unsigned short* qb = Qp + ((size_t)bh * LQ + qrow16 + l16) * 64 + 8 * g;
    qf[0] = *(const bf16x8*)qb;
    qf[1] = *(const bf16x8*)(qb + 32);
  }

  float m_run[4], l_run[4];
  f32x4 o[3];
#pragma unroll
  for (int r = 0; r < 4; ++r) { m_run[r] = -1e30f; l_run[r] = 0.f; }
#pragma unroll
  for (int d = 0; d < 3; ++d) { f32x4 z = {0.f, 0.f, 0.f, 0.f}; o[d] = z; }

  const char* kbase = (const char*)(Kp + (size_t)bh * LKVP * 64);
  const char* vbase = (const char*)(Vt + (size_t)bh * 48 * LKVP);
  const unsigned short* pb16 =
      posb + (((size_t)h * 64 + (m0 >> 4) + wave) * NKVT * 64 + lane) * 16;
  unsigned short* pb = &Psh[wave][0];

  // prologue: stage tile 0, prefetch pos tile 0
  bf16x8 pr0 = *(const bf16x8*)(pb16);
  bf16x8 pr1 = *(const bf16x8*)(pb16 + 8);
  stage_tile(kbase, vbase, 0, (char*)&Ksh[0][0], (char*)&Vsh[0][0], wave, lane);
  asm volatile("s_waitcnt vmcnt(0)" ::: "memory");
  __syncthreads();

  int buf = 0;
  for (int t = 0; t < NKVT; ++t) {
    const int nxt = t + 1;
    if (nxt < NKVT)
      stage_tile(kbase, vbase, nxt, (char*)&Ksh[buf ^ 1][0], (char*)&Vsh[buf ^ 1][0],
                 wave, lane);

    // convert pos tile t (already in regs), then prefetch pos tile t+1
    float pf[4][4];
#pragma unroll
    for (int v = 0; v < 16; ++v) {
      unsigned short u = (unsigned short)((v < 8) ? pr0[v] : pr1[v - 8]);
      pf[v >> 2][v & 3] = b2f(u);
    }
    if (nxt < NKVT) {
      pr0 = *(const bf16x8*)(pb16 + (size_t)nxt * 1024);
      pr1 = *(const bf16x8*)(pb16 + (size_t)nxt * 1024 + 8);
    }

    // QK^T
    f32x4 s[4];
#pragma unroll
    for (int ni = 0; ni < 4; ++ni) { f32x4 z = {0.f, 0.f, 0.f, 0.f}; s[ni] = z; }
#pragma unroll
    for (int ni = 0; ni < 4; ++ni) {
      const int krow = ni * 16 + l16;
#pragma unroll
      for (int kk = 0; kk < 2; ++kk) {
        bf16x8 kf = *(const bf16x8*)((const char*)&Ksh[buf][0] + krow * 128 +
                                     (((g + 4 * kk) ^ (krow & 7)) << 4));
        s[ni] = __builtin_amdgcn_mfma_f32_16x16x32_bf16(qf[kk], kf, s[ni], 0, 0, 0);
      }
    }

    // online softmax in exp2 domain (log2e folded into Q scale and pos)
    float p[4][4];
#pragma unroll
    for (int r = 0; r < 4; ++r) {
      float x0 = s[0][r] + pf[0][r], x1 = s[1][r] + pf[1][r];
      float x2 = s[2][r] + pf[2][r], x3 = s[3][r] + pf[3][r];
      float mx = fmaxf(fmaxf(x0, x1), fmaxf(x2, x3));
      mx = fmaxf(mx, __shfl_xor(mx, 1));
      mx = fmaxf(mx, __shfl_xor(mx, 2));
      mx = fmaxf(mx, __shfl_xor(mx, 4));
      mx = fmaxf(mx, __shfl_xor(mx, 8));
      const float mn = fmaxf(m_run[r], mx);
      const float al = exp2f(m_run[r] - mn);
      const float e0 = exp2f(x0 - mn), e1 = exp2f(x1 - mn);
      const float e2 = exp2f(x2 - mn), e3 = exp2f(x3 - mn);
      p[0][r] = e0; p[1][r] = e1; p[2][r] = e2; p[3][r] = e3;
      float rs = (e0 + e1) + (e2 + e3);
      rs += __shfl_xor(rs, 1);
      rs += __shfl_xor(rs, 2);
      rs += __shfl_xor(rs, 4);
      rs += __shfl_xor(rs, 8);
      l_run[r] = l_run[r] * al + rs;
      m_run[r] = mn;
      o[0][r] *= al; o[1][r] *= al; o[2][r] *= al;
    }

    // P -> per-wave LDS (swizzled), read back as A fragments
#pragma unroll
    for (int ni = 0; ni < 4; ++ni) {
      const int col = ni * 16 + l16;
#pragma unroll
      for (int r = 0; r < 4; ++r) {
        const int row = 4 * g + r;
        pb[row * 64 + (((col >> 3) ^ (row & 7)) << 3) + (col & 7)] = f2b(p[ni][r]);
      }
    }
    bf16x8 af[2];
#pragma unroll
    for (int kk = 0; kk < 2; ++kk)
      af[kk] = *(const bf16x8*)((const char*)pb + l16 * 128 +
                                (((g + 4 * kk) ^ (l16 & 7)) << 4));

    // P @ V from LDS (swizzled V^T tile)
#pragma unroll
    for (int dn = 0; dn < 3; ++dn) {
#pragma unroll
      for (int kk = 0; kk < 2; ++kk) {
        const int vr = l16 + 16 * dn;
        bf16x8 vf = *(const bf16x8*)((const char*)&Vsh[buf][0] + vr * 128 +
                                     (((g + 4 * kk) ^ (vr & 7)) << 4));
        o[dn] = __builtin_amdgcn_mfma_f32_16x16x32_bf16(af[kk], vf, o[dn], 0, 0, 0);
      }
    }

    asm volatile("s_waitcnt vmcnt(0)" ::: "memory");
    __syncthreads();
    buf ^= 1;
  }

#pragma unroll
  for (int r = 0; r < 4; ++r) {
    const float inv = 1.f / l_run[r];
    const int m = qrow16 + 4 * g + r;
    unsigned short* xp = X + ((size_t)b * LQ + m) * DIMC + h * 48 + l16;
    xp[0] = f2b(o[0][r] * inv);
    xp[16] = f2b(o[1][r] * inv);
    xp[32] = f2b(o[2][r] * inv);
  }
}

// ---------------- launch ----------------
extern "C" void kernel_launch(void* const* d_in, const int* in_sizes, int n_in,
                              void* d_out, int out_size, void* d_ws, size_t ws_size,
                              hipStream_t stream) {
  const float* tem  = (const float*)d_in[0];
  const float* srch = (const float*)d_in[1];
  const float* q    = (const float*)d_in[2];
  const float* kv   = (const float*)d_in[3];
  const float* pos  = (const float*)d_in[4];
  const float* q_w  = (const float*)d_in[5];
  const float* q_b  = (const float*)d_in[6];
  const float* kv_w = (const float*)d_in[7];
  const float* kv_b = (const float*)d_in[8];
  const float* p_w  = (const float*)d_in[9];
  const float* p_b  = (const float*)d_in[10];
  float* out = (float*)d_out;

  char* w = (char*)d_ws;
  unsigned short* Qp   = (unsigned short*)(w);             // 16.8 MB (B*H,LQ,64)
  unsigned short* Kp   = (unsigned short*)(w + 16777216);  // 24.1 MB (B*H,LKVP,64) swz
  unsigned short* Vt   = (unsigned short*)(w + 40894464);  // 18.1 MB (B*H,48,LKVP) swz
  unsigned short* X    = (unsigned short*)(w + 58982400);  // 12.6 MB (B*LQ,DIMC)
  unsigned short* posb = (unsigned short*)(w + 71565312);  // 24.1 MB fragment-ordered pos

  init_ws<<<14400, 256, 0, stream>>>((u32x4*)w, 3686400);  // zero Qp+Kp+Vt (pads)
  prep_pos<<<dim3(NKVT, 16, NH), 256, 0, stream>>>(pos, posb);
  proj_gemm<0><<<dim3(6, 256), 256, 0, stream>>>(q, nullptr, q_w, q_b, nullptr, nullptr,
                                                 Qp, nullptr, nullptr, nullptr);
  proj_gemm<1><<<dim3(12, 356), 256, 0, stream>>>(kv, nullptr, kv_w, kv_b, tem, srch,
                                                  nullptr, Kp, Vt, nullptr);
  attn_fwd<<<dim3(16, 8, 16), 256, 0, stream>>>(posb, Qp, Kp, Vt, X);
  proj_gemm<2><<<dim3(6, 256), 256, 0, stream>>>(nullptr, X, p_w, p_b, nullptr, nullptr,
                                                 nullptr, nullptr, nullptr, out);
}

// Round 3
// 295.441 us; speedup vs baseline: 1.1761x; 1.1666x over previous
//
#include <hip/hip_runtime.h>
#include <stdint.h>

#define NB 16
#define NH 8
#define LQ 1024
#define LKV 1424
#define LKVP 1472
#define DIMC 384
#define NKVT 23
#define TEM 400
#define QSCALE 0.20823509f       // (1/sqrt(48)) * log2(e)
#define LOG2E_F 1.4426950408889634f

typedef __attribute__((ext_vector_type(4))) float f32x4;
typedef __attribute__((ext_vector_type(8))) short bf16x8;
typedef __attribute__((ext_vector_type(4))) unsigned short us4;
typedef __attribute__((ext_vector_type(4))) unsigned int u32x4;

__device__ __forceinline__ unsigned short f2b(float f) {
  unsigned int u = __builtin_bit_cast(unsigned int, f);
  u += 0x7fffu + ((u >> 16) & 1u);  // round-to-nearest-even
  return (unsigned short)(u >> 16);
}
__device__ __forceinline__ float b2f(unsigned short u) {
  return __builtin_bit_cast(float, (unsigned int)u << 16);
}

__device__ __forceinline__ void gload_lds16(const void* gsrc, void* ldst) {
  __builtin_amdgcn_global_load_lds(
      (const __attribute__((address_space(1))) void*)gsrc,
      (__attribute__((address_space(3))) void*)ldst, 16, 0, 0);
}

// ---------- convert f32 [R][384] -> bf16 pre-swizzled (chunk ^= row&7 per 64-col blk) ----------
__global__ __launch_bounds__(256) void conv_swz(const float* __restrict__ in,
                                                unsigned short* __restrict__ out, int nch) {
  int i = blockIdx.x * 256 + threadIdx.x;
  if (i >= nch) return;
  int row = i / 48, ch = i - row * 48;
  const float* src = in + (size_t)row * DIMC + ch * 8;
  f32x4 x = *(const f32x4*)src;
  f32x4 y = *(const f32x4*)(src + 4);
  bf16x8 o;
  o[0] = (short)f2b(x[0]); o[1] = (short)f2b(x[1]);
  o[2] = (short)f2b(x[2]); o[3] = (short)f2b(x[3]);
  o[4] = (short)f2b(y[0]); o[5] = (short)f2b(y[1]);
  o[6] = (short)f2b(y[2]); o[7] = (short)f2b(y[3]);
  int blk = ch >> 3, c3 = (ch & 7) ^ (row & 7);
  *(bf16x8*)(out + (size_t)row * DIMC + blk * 64 + c3 * 8) = o;
}

// ---------- exact pad zeroing ----------
__global__ __launch_bounds__(256) void zero_qpad(unsigned short* Qp) {
  int r = blockIdx.x * 256 + threadIdx.x;  // 131072 rows
  u32x4 z = {0u, 0u, 0u, 0u};
  *(u32x4*)(Qp + (size_t)r * 64 + 48) = z;
  *(u32x4*)(Qp + (size_t)r * 64 + 56) = z;
}
__global__ __launch_bounds__(256) void zero_kpad(unsigned short* Kp) {
  int r = blockIdx.x * 256 + threadIdx.x;  // 128*1472 rows
  int s = r % LKVP;
  unsigned short* row = Kp + (size_t)r * 64;
  u32x4 z = {0u, 0u, 0u, 0u};
  if (s < LKV) {
    *(u32x4*)(row + (6 ^ (s & 7)) * 8) = z;
    *(u32x4*)(row + (7 ^ (s & 7)) * 8) = z;
  } else {
#pragma unroll
    for (int c = 0; c < 64; c += 8) *(u32x4*)(row + c) = z;
  }
}
__global__ __launch_bounds__(256) void zero_vpad(unsigned short* Vt) {
  int i = blockIdx.x * 256 + threadIdx.x;  // 6144 rows * 6 chunks
  int row = i / 6, x = 2 + i - (i / 6) * 6;
  int d = row % 48;
  u32x4 z = {0u, 0u, 0u, 0u};
  *(u32x4*)(Vt + (size_t)row * LKVP + 1408 + ((x ^ d) & 7) * 8) = z;
}

// ---------- pos prep: f32 -> bf16, *log2e, fragment-ordered, padded ----------
__global__ __launch_bounds__(256) void prep_pos(const float* __restrict__ pos,
                                                unsigned short* __restrict__ posb) {
  const int t = blockIdx.x, h = blockIdx.z;
  const int wave = threadIdx.x >> 6, lane = threadIdx.x & 63;
  const int q16 = blockIdx.y * 4 + wave;
  const int l16 = lane & 15, g = lane >> 4;
  unsigned short vals[16];
#pragma unroll
  for (int ni = 0; ni < 4; ++ni) {
    const int col = t * 64 + ni * 16 + l16;
#pragma unroll
    for (int r = 0; r < 4; ++r) {
      const int q = q16 * 16 + 4 * g + r;
      float v = (col < LKV) ? pos[((size_t)h * LQ + q) * LKV + col] * LOG2E_F : -1e30f;
      vals[ni * 4 + r] = f2b(v);
    }
  }
  unsigned short* op = posb + ((((size_t)h * 64 + q16) * NKVT + t) * 64 + lane) * 16;
  bf16x8 a, b;
#pragma unroll
  for (int i = 0; i < 8; ++i) { a[i] = (short)vals[i]; b[i] = (short)vals[8 + i]; }
  *(bf16x8*)op = a;
  *(bf16x8*)(op + 8) = b;
}

// ---------- projection GEMMs: 128x128 tile, BK=64, gload_lds staging ----------
// A [M][384] bf16 pre-swizzled, Wb [N][384] bf16 pre-swizzled.
// MODE 0: -> Qp ((b,h),Lq,64) * QSCALE   MODE 1: -> Kp swz / Vt^T swz + mask
// MODE 2: -> out f32
template <int MODE>
__global__ __launch_bounds__(256) void proj_gemm(
    const unsigned short* __restrict__ A, const unsigned short* __restrict__ Wb,
    const float* __restrict__ bias, const float* __restrict__ tem,
    const float* __restrict__ srch, unsigned short* __restrict__ Oq,
    unsigned short* __restrict__ Ok, unsigned short* __restrict__ Ovt,
    float* __restrict__ Of) {
  __shared__ unsigned short Ash[128 * 64];
  __shared__ unsigned short Bsh[128 * 64];
  const int tid = threadIdx.x;
  const int lane = tid & 63, l16 = lane & 15, g = lane >> 4;
  const int wave = tid >> 6, wm = wave >> 1, wn = wave & 1;
  const int n0 = blockIdx.x * 128, m0 = blockIdx.y * 128;

  f32x4 acc[4][4];
#pragma unroll
  for (int i = 0; i < 4; ++i)
#pragma unroll
    for (int j = 0; j < 4; ++j) { f32x4 z = {0.f, 0.f, 0.f, 0.f}; acc[i][j] = z; }

  const char* Abase = (const char*)A + (size_t)m0 * 768;
  const char* Bbase = (const char*)Wb + (size_t)n0 * 768;

  for (int ks = 0; ks < 6; ++ks) {
    __syncthreads();
#pragma unroll
    for (int rnd = 0; rnd < 4; ++rnd) {
      int idx = tid + rnd * 256;               // idx = row*8 + chunk
      int row = idx >> 3, chunk = idx & 7;
      gload_lds16(Abase + (size_t)row * 768 + ks * 128 + chunk * 16,
                  (char*)Ash + idx * 16);
    }
#pragma unroll
    for (int rnd = 0; rnd < 4; ++rnd) {
      int idx = tid + rnd * 256;
      int row = idx >> 3, chunk = idx & 7;
      gload_lds16(Bbase + (size_t)row * 768 + ks * 128 + chunk * 16,
                  (char*)Bsh + idx * 16);
    }
    asm volatile("s_waitcnt vmcnt(0)" ::: "memory");
    __syncthreads();
#pragma unroll
    for (int kk = 0; kk < 2; ++kk) {
      bf16x8 a[4], bb[4];
#pragma unroll
      for (int mi = 0; mi < 4; ++mi) {
        int row = wm * 64 + mi * 16 + l16;
        a[mi] = *(const bf16x8*)((char*)Ash + row * 128 + (((g + 4 * kk) ^ (row & 7)) << 4));
      }
#pragma unroll
      for (int ni = 0; ni < 4; ++ni) {
        int row = wn * 64 + ni * 16 + l16;
        bb[ni] = *(const bf16x8*)((char*)Bsh + row * 128 + (((g + 4 * kk) ^ (row & 7)) << 4));
      }
#pragma unroll
      for (int mi = 0; mi < 4; ++mi)
#pragma unroll
        for (int ni = 0; ni < 4; ++ni)
          acc[mi][ni] = __builtin_amdgcn_mfma_f32_16x16x32_bf16(a[mi], bb[ni], acc[mi][ni], 0, 0, 0);
    }
  }

#pragma unroll
  for (int mi = 0; mi < 4; ++mi) {
    const int m_g0 = m0 + wm * 64 + mi * 16 + 4 * g;  // 4-aligned
#pragma unroll
    for (int ni = 0; ni < 4; ++ni) {
      const int n_g = n0 + wn * 64 + ni * 16 + l16;
      const float bv = bias[n_g];
      if (MODE == 0) {
        const int hh = n_g / 48, d = n_g - hh * 48;
#pragma unroll
        for (int r = 0; r < 4; ++r) {
          const int m_g = m_g0 + r;
          const int b = m_g >> 10, m = m_g & 1023;
          Oq[(((size_t)b * NH + hh) * LQ + m) * 64 + d] = f2b((acc[mi][ni][r] + bv) * QSCALE);
        }
      } else if (MODE == 2) {
#pragma unroll
        for (int r = 0; r < 4; ++r)
          Of[(size_t)(m_g0 + r) * DIMC + n_g] = acc[mi][ni][r] + bv;
      } else {
        const int b = m_g0 / LKV, s0 = m_g0 - b * LKV;  // 4-group never crosses batch (1424%4==0)
        if (n_g < DIMC) {
          const int hh = n_g / 48, d = n_g - hh * 48;
#pragma unroll
          for (int r = 0; r < 4; ++r) {
            const int s = s0 + r;
            const int dsw = (d & 7) | ((((d >> 3) ^ (s & 7)) & 7) << 3);
            Ok[(((size_t)b * NH + hh) * LKVP + s) * 64 + dsw] = f2b(acc[mi][ni][r] + bv);
          }
        } else {
          const int c = n_g - DIMC, hh = c / 48, d = c - hh * 48;
          const float* mb = (s0 < TEM)
                                ? tem + ((size_t)b * TEM + s0) * DIMC + c
                                : srch + ((size_t)b * (LKV - TEM) + (s0 - TEM)) * DIMC + c;
          const int off = s0 & 63;
          const int soff = (s0 & ~63) | ((((off >> 3) ^ d) & 7) << 3) | (off & 7);
          us4 pk;
#pragma unroll
          for (int r = 0; r < 4; ++r)
            pk[r] = f2b(acc[mi][ni][r] + bv + mb[(size_t)r * DIMC]);
          *(us4*)(Ovt + (((size_t)b * NH + hh) * 48 + d) * LKVP + soff) = pk;
        }
      }
    }
  }
}

// ---------------- flash attention (double-buffered K+V in LDS, bf16 pos) ----------------
__device__ __forceinline__ void stage_tile(const char* kbase, const char* vbase, int t,
                                           char* kdst, char* vdst, int wave, int lane) {
  const char* ks = kbase + (size_t)t * 8192 + wave * 2048 + lane * 16;
  char* kd = kdst + wave * 2048;
  gload_lds16(ks, kd);
  gload_lds16(ks + 1024, kd + 1024);
  if (wave < 3) {  // V tile: 48 rows x 128B
    const char* vs = vbase + (size_t)(wave * 16 + (lane >> 3)) * (LKVP * 2) +
                     (size_t)t * 128 + (lane & 7) * 16;
    char* vd = vdst + wave * 2048;
    gload_lds16(vs, vd);
    gload_lds16(vs + 8 * (LKVP * 2), vd + 1024);
  }
}

__global__ __launch_bounds__(256) void attn_fwd(
    const unsigned short* __restrict__ posb, const unsigned short* __restrict__ Qp,
    const unsigned short* __restrict__ Kp, const unsigned short* __restrict__ Vt,
    unsigned short* __restrict__ X) {
  __shared__ unsigned short Ksh[2][64 * 64];
  __shared__ unsigned short Vsh[2][48 * 64];
  __shared__ unsigned short Psh[4][16 * 64];

  const int tid = threadIdx.x;
  const int lane = tid & 63, l16 = lane & 15, g = lane >> 4;
  const int wave = tid >> 6;
  const int h = blockIdx.y, b = blockIdx.z;
  const int bh = b * NH + h;
  const int m0 = blockIdx.x * 64;
  const int qrow16 = m0 + wave * 16;

  bf16x8 qf[2];
  {
    const unsigned short* qb = Qp + ((size_t)bh * LQ + qrow16 + l16) * 64 + 8 * g;
    qf[0] = *(const bf16x8*)qb;
    qf[1] = *(const bf16x8*)(qb + 32);
  }

  float m_run[4], l_run[4];
  f32x4 o[3];
#pragma unroll
  for (int r = 0; r < 4; ++r) { m_run[r] = -1e30f; l_run[r] = 0.f; }
#pragma unroll
  for (int d = 0; d < 3; ++d) { f32x4 z = {0.f, 0.f, 0.f, 0.f}; o[d] = z; }

  const char* kbase = (const char*)(Kp + (size_t)bh * LKVP * 64);
  const char* vbase = (const char*)(Vt + (size_t)bh * 48 * LKVP);
  const unsigned short* pb16 =
      posb + (((size_t)h * 64 + (m0 >> 4) + wave) * NKVT * 64 + lane) * 16;
  unsigned short* pb = &Psh[wave][0];

  bf16x8 pr0 = *(const bf16x8*)(pb16);
  bf16x8 pr1 = *(const bf16x8*)(pb16 + 8);
  stage_tile(kbase, vbase, 0, (char*)&Ksh[0][0], (char*)&Vsh[0][0], wave, lane);
  asm volatile("s_waitcnt vmcnt(0)" ::: "memory");
  __syncthreads();

  int buf = 0;
  for (int t = 0; t < NKVT; ++t) {
    const int nxt = t + 1;
    if (nxt < NKVT)
      stage_tile(kbase, vbase, nxt, (char*)&Ksh[buf ^ 1][0], (char*)&Vsh[buf ^ 1][0],
                 wave, lane);

    float pf[4][4];
#pragma unroll
    for (int v = 0; v < 16; ++v) {
      unsigned short u = (unsigned short)((v < 8) ? pr0[v] : pr1[v - 8]);
      pf[v >> 2][v & 3] = b2f(u);
    }
    if (nxt < NKVT) {
      pr0 = *(const bf16x8*)(pb16 + (size_t)nxt * 1024);
      pr1 = *(const bf16x8*)(pb16 + (size_t)nxt * 1024 + 8);
    }

    f32x4 s[4];
#pragma unroll
    for (int ni = 0; ni < 4; ++ni) { f32x4 z = {0.f, 0.f, 0.f, 0.f}; s[ni] = z; }
#pragma unroll
    for (int ni = 0; ni < 4; ++ni) {
      const int krow = ni * 16 + l16;
#pragma unroll
      for (int kk = 0; kk < 2; ++kk) {
        bf16x8 kf = *(const bf16x8*)((const char*)&Ksh[buf][0] + krow * 128 +
                                     (((g + 4 * kk) ^ (krow & 7)) << 4));
        s[ni] = __builtin_amdgcn_mfma_f32_16x16x32_bf16(qf[kk], kf, s[ni], 0, 0, 0);
      }
    }

    float p[4][4];
#pragma unroll
    for (int r = 0; r < 4; ++r) {
      float x0 = s[0][r] + pf[0][r], x1 = s[1][r] + pf[1][r];
      float x2 = s[2][r] + pf[2][r], x3 = s[3][r] + pf[3][r];
      float mx = fmaxf(fmaxf(x0, x1), fmaxf(x2, x3));
      mx = fmaxf(mx, __shfl_xor(mx, 1));
      mx = fmaxf(mx, __shfl_xor(mx, 2));
      mx = fmaxf(mx, __shfl_xor(mx, 4));
      mx = fmaxf(mx, __shfl_xor(mx, 8));
      const float mn = fmaxf(m_run[r], mx);
      const float al = exp2f(m_run[r] - mn);
      const float e0 = exp2f(x0 - mn), e1 = exp2f(x1 - mn);
      const float e2 = exp2f(x2 - mn), e3 = exp2f(x3 - mn);
      p[0][r] = e0; p[1][r] = e1; p[2][r] = e2; p[3][r] = e3;
      float rs = (e0 + e1) + (e2 + e3);
      rs += __shfl_xor(rs, 1);
      rs += __shfl_xor(rs, 2);
      rs += __shfl_xor(rs, 4);
      rs += __shfl_xor(rs, 8);
      l_run[r] = l_run[r] * al + rs;
      m_run[r] = mn;
      o[0][r] *= al; o[1][r] *= al; o[2][r] *= al;
    }

#pragma unroll
    for (int ni = 0; ni < 4; ++ni) {
      const int col = ni * 16 + l16;
#pragma unroll
      for (int r = 0; r < 4; ++r) {
        const int row = 4 * g + r;
        pb[row * 64 + (((col >> 3) ^ (row & 7)) << 3) + (col & 7)] = f2b(p[ni][r]);
      }
    }
    bf16x8 af[2];
#pragma unroll
    for (int kk = 0; kk < 2; ++kk)
      af[kk] = *(const bf16x8*)((const char*)pb + l16 * 128 +
                                (((g + 4 * kk) ^ (l16 & 7)) << 4));

#pragma unroll
    for (int dn = 0; dn < 3; ++dn) {
#pragma unroll
      for (int kk = 0; kk < 2; ++kk) {
        const int vr = l16 + 16 * dn;
        bf16x8 vf = *(const bf16x8*)((const char*)&Vsh[buf][0] + vr * 128 +
                                     (((g + 4 * kk) ^ (vr & 7)) << 4));
        o[dn] = __builtin_amdgcn_mfma_f32_16x16x32_bf16(af[kk], vf, o[dn], 0, 0, 0);
      }
    }

    asm volatile("s_waitcnt vmcnt(0)" ::: "memory");
    __syncthreads();
    buf ^= 1;
  }

#pragma unroll
  for (int r = 0; r < 4; ++r) {
    const float inv = 1.f / l_run[r];
    const int m = qrow16 + 4 * g + r;
#pragma unroll
    for (int dn = 0; dn < 3; ++dn) {
      const int c = h * 48 + 16 * dn + l16;
      const int cs = (c & ~63) | (c & 7) | ((((c >> 3) & 7) ^ (m & 7)) << 3);  // pre-swz for out-proj
      X[((size_t)b * LQ + m) * DIMC + cs] = f2b(o[dn][r] * inv);
    }
  }
}

// ---------------- launch ----------------
extern "C" void kernel_launch(void* const* d_in, const int* in_sizes, int n_in,
                              void* d_out, int out_size, void* d_ws, size_t ws_size,
                              hipStream_t stream) {
  const float* tem  = (const float*)d_in[0];
  const float* srch = (const float*)d_in[1];
  const float* q    = (const float*)d_in[2];
  const float* kv   = (const float*)d_in[3];
  const float* pos  = (const float*)d_in[4];
  const float* q_w  = (const float*)d_in[5];
  const float* q_b  = (const float*)d_in[6];
  const float* kv_w = (const float*)d_in[7];
  const float* kv_b = (const float*)d_in[8];
  const float* p_w  = (const float*)d_in[9];
  const float* p_b  = (const float*)d_in[10];
  float* out = (float*)d_out;

  char* w = (char*)d_ws;
  unsigned short* Qp   = (unsigned short*)(w);              // 16.8 MB (b,h,Lq,64)
  unsigned short* Kp   = (unsigned short*)(w + 16777216);   // 24.1 MB (b,h,LKVP,64) swz
  unsigned short* Vt   = (unsigned short*)(w + 40894464);   // 18.1 MB (b,h,48,LKVP) swz
  unsigned short* X    = (unsigned short*)(w + 58982400);   // 12.6 MB (B*LQ,384) swz — aliases qb
  unsigned short* qb   = X;                                 //   (dead before attn writes X)
  unsigned short* posb = (unsigned short*)(w + 71565312);   // 24.1 MB fragment-ordered pos
  unsigned short* kvb  = (unsigned short*)(w + 95682560);   // 17.5 MB
  unsigned short* qwb  = (unsigned short*)(w + 113180672);  // 0.3 MB
  unsigned short* kvwb = (unsigned short*)(w + 113475584);  // 0.6 MB
  unsigned short* pwb  = (unsigned short*)(w + 114065408);  // 0.3 MB

  conv_swz<<<3072, 256, 0, stream>>>(q, qb, 16384 * 48);
  conv_swz<<<4272, 256, 0, stream>>>(kv, kvb, 22784 * 48);
  conv_swz<<<72, 256, 0, stream>>>(q_w, qwb, 384 * 48);
  conv_swz<<<144, 256, 0, stream>>>(kv_w, kvwb, 768 * 48);
  conv_swz<<<72, 256, 0, stream>>>(p_w, pwb, 384 * 48);
  zero_qpad<<<512, 256, 0, stream>>>(Qp);
  zero_kpad<<<736, 256, 0, stream>>>(Kp);
  zero_vpad<<<144, 256, 0, stream>>>(Vt);
  prep_pos<<<dim3(NKVT, 16, NH), 256, 0, stream>>>(pos, posb);
  proj_gemm<0><<<dim3(3, 128), 256, 0, stream>>>(qb, qwb, q_b, nullptr, nullptr,
                                                 Qp, nullptr, nullptr, nullptr);
  proj_gemm<1><<<dim3(6, 178), 256, 0, stream>>>(kvb, kvwb, kv_b, tem, srch,
                                                 nullptr, Kp, Vt, nullptr);
  attn_fwd<<<dim3(16, 8, 16), 256, 0, stream>>>(posb, Qp, Kp, Vt, X);
  proj_gemm<2><<<dim3(3, 128), 256, 0, stream>>>(X, pwb, p_b, nullptr, nullptr,
                                                 nullptr, nullptr, nullptr, out);
}

// Round 4
// 232.958 us; speedup vs baseline: 1.4915x; 1.2682x over previous
//
#include <hip/hip_runtime.h>
#include <stdint.h>

#define NB 16
#define NH 8
#define LQ 1024
#define LKV 1424
#define LKVP 1472
#define DIMC 384
#define NKVT 23
#define TEM 400
#define QSCALE 0.20823509f       // (1/sqrt(48)) * log2(e)
#define LOG2E_F 1.4426950408889634f

typedef __attribute__((ext_vector_type(4))) float f32x4;
typedef __attribute__((ext_vector_type(8))) short bf16x8;
typedef __attribute__((ext_vector_type(4))) unsigned short us4;
typedef __attribute__((ext_vector_type(2))) unsigned int u32x2;
typedef __attribute__((ext_vector_type(4))) unsigned int u32x4;

__device__ __forceinline__ unsigned short f2b(float f) {
  unsigned int u = __builtin_bit_cast(unsigned int, f);
  u += 0x7fffu + ((u >> 16) & 1u);  // round-to-nearest-even
  return (unsigned short)(u >> 16);
}
__device__ __forceinline__ float b2f(unsigned short u) {
  return __builtin_bit_cast(float, (unsigned int)u << 16);
}

__device__ __forceinline__ void gload_lds16(const void* gsrc, void* ldst) {
  __builtin_amdgcn_global_load_lds(
      (const __attribute__((address_space(1))) void*)gsrc,
      (__attribute__((address_space(3))) void*)ldst, 16, 0, 0);
}

// ---------- convert f32 [R][384] -> bf16 pre-swizzled (chunk ^= row&7 per 64-col blk) ----------
__global__ __launch_bounds__(256) void conv_swz(const float* __restrict__ in,
                                                unsigned short* __restrict__ out, int nch) {
  int i = blockIdx.x * 256 + threadIdx.x;
  if (i >= nch) return;
  int row = i / 48, ch = i - row * 48;
  const float* src = in + (size_t)row * DIMC + ch * 8;
  f32x4 x = *(const f32x4*)src;
  f32x4 y = *(const f32x4*)(src + 4);
  bf16x8 o;
  o[0] = (short)f2b(x[0]); o[1] = (short)f2b(x[1]);
  o[2] = (short)f2b(x[2]); o[3] = (short)f2b(x[3]);
  o[4] = (short)f2b(y[0]); o[5] = (short)f2b(y[1]);
  o[6] = (short)f2b(y[2]); o[7] = (short)f2b(y[3]);
  int blk = ch >> 3, c3 = (ch & 7) ^ (row & 7);
  *(bf16x8*)(out + (size_t)row * DIMC + blk * 64 + c3 * 8) = o;
}

// ---------- exact pad zeroing (NaN safety: pads must be finite/zero) ----------
__global__ __launch_bounds__(256) void zero_qpad(unsigned short* Qp) {
  int r = blockIdx.x * 256 + threadIdx.x;  // 131072 rows
  u32x4 z = {0u, 0u, 0u, 0u};
  *(u32x4*)(Qp + (size_t)r * 64 + 48) = z;
  *(u32x4*)(Qp + (size_t)r * 64 + 56) = z;
}
__global__ __launch_bounds__(256) void zero_kpad(unsigned short* Kp) {
  int r = blockIdx.x * 256 + threadIdx.x;  // 128*1472 rows
  int s = r % LKVP;
  unsigned short* row = Kp + (size_t)r * 64;
  u32x4 z = {0u, 0u, 0u, 0u};
  if (s < LKV) {
    *(u32x4*)(row + (6 ^ (s & 7)) * 8) = z;
    *(u32x4*)(row + (7 ^ (s & 7)) * 8) = z;
  } else {
#pragma unroll
    for (int c = 0; c < 64; c += 8) *(u32x4*)(row + c) = z;
  }
}
__global__ __launch_bounds__(256) void zero_vpad(unsigned short* Vt) {
  int i = blockIdx.x * 256 + threadIdx.x;  // 6144 rows * 6 chunks
  int row = i / 6, x = 2 + i - (i / 6) * 6;
  int d = row % 48;
  u32x4 z = {0u, 0u, 0u, 0u};
  *(u32x4*)(Vt + (size_t)row * LKVP + 1408 + ((x ^ d) & 7) * 8) = z;
}

// ---------- pos prep: f32 -> bf16, *log2e, swapped-fragment order, padded ----------
// posb[((h*64+q16)*23 + t)*64 + lane]*16 + (ni*4+r) = pos[h][q16*16+l16][t*64+16ni+4g+r]
__global__ __launch_bounds__(256) void prep_pos(const float* __restrict__ pos,
                                                unsigned short* __restrict__ posb) {
  const int t = blockIdx.x, h = blockIdx.z;
  const int wave = threadIdx.x >> 6, lane = threadIdx.x & 63;
  const int q16 = blockIdx.y * 4 + wave;
  const int l16 = lane & 15, g = lane >> 4;
  const int q = q16 * 16 + l16;
  const float* pr = pos + ((size_t)h * LQ + q) * LKV;
  unsigned short vals[16];
  const unsigned short NEG = f2b(-1e30f);
#pragma unroll
  for (int ni = 0; ni < 4; ++ni) {
    if (t * 64 + ni * 16 < LKV) {
      f32x4 v = *(const f32x4*)(pr + t * 64 + ni * 16 + 4 * g);
#pragma unroll
      for (int r = 0; r < 4; ++r) vals[ni * 4 + r] = f2b(v[r] * LOG2E_F);
    } else {
#pragma unroll
      for (int r = 0; r < 4; ++r) vals[ni * 4 + r] = NEG;
    }
  }
  unsigned short* op = posb + ((((size_t)h * 64 + q16) * NKVT + t) * 64 + lane) * 16;
  bf16x8 a, b;
#pragma unroll
  for (int i = 0; i < 8; ++i) { a[i] = (short)vals[i]; b[i] = (short)vals[8 + i]; }
  *(bf16x8*)op = a;
  *(bf16x8*)(op + 8) = b;
}

// ---------- projection GEMMs: 128x128 tile, BK=64, gload_lds staging ----------
template <int MODE>
__global__ __launch_bounds__(256) void proj_gemm(
    const unsigned short* __restrict__ A, const unsigned short* __restrict__ Wb,
    const float* __restrict__ bias, const float* __restrict__ tem,
    const float* __restrict__ srch, unsigned short* __restrict__ Oq,
    unsigned short* __restrict__ Ok, unsigned short* __restrict__ Ovt,
    float* __restrict__ Of) {
  __shared__ unsigned short Ash[128 * 64];
  __shared__ unsigned short Bsh[128 * 64];
  const int tid = threadIdx.x;
  const int lane = tid & 63, l16 = lane & 15, g = lane >> 4;
  const int wave = tid >> 6, wm = wave >> 1, wn = wave & 1;
  const int n0 = blockIdx.x * 128, m0 = blockIdx.y * 128;

  f32x4 acc[4][4];
#pragma unroll
  for (int i = 0; i < 4; ++i)
#pragma unroll
    for (int j = 0; j < 4; ++j) { f32x4 z = {0.f, 0.f, 0.f, 0.f}; acc[i][j] = z; }

  const char* Abase = (const char*)A + (size_t)m0 * 768;
  const char* Bbase = (const char*)Wb + (size_t)n0 * 768;

  for (int ks = 0; ks < 6; ++ks) {
    __syncthreads();
#pragma unroll
    for (int rnd = 0; rnd < 4; ++rnd) {
      int idx = tid + rnd * 256;
      int row = idx >> 3, chunk = idx & 7;
      gload_lds16(Abase + (size_t)row * 768 + ks * 128 + chunk * 16,
                  (char*)Ash + idx * 16);
    }
#pragma unroll
    for (int rnd = 0; rnd < 4; ++rnd) {
      int idx = tid + rnd * 256;
      int row = idx >> 3, chunk = idx & 7;
      gload_lds16(Bbase + (size_t)row * 768 + ks * 128 + chunk * 16,
                  (char*)Bsh + idx * 16);
    }
    asm volatile("s_waitcnt vmcnt(0)" ::: "memory");
    __syncthreads();
#pragma unroll
    for (int kk = 0; kk < 2; ++kk) {
      bf16x8 a[4], bb[4];
#pragma unroll
      for (int mi = 0; mi < 4; ++mi) {
        int row = wm * 64 + mi * 16 + l16;
        a[mi] = *(const bf16x8*)((char*)Ash + row * 128 + (((g + 4 * kk) ^ (row & 7)) << 4));
      }
#pragma unroll
      for (int ni = 0; ni < 4; ++ni) {
        int row = wn * 64 + ni * 16 + l16;
        bb[ni] = *(const bf16x8*)((char*)Bsh + row * 128 + (((g + 4 * kk) ^ (row & 7)) << 4));
      }
#pragma unroll
      for (int mi = 0; mi < 4; ++mi)
#pragma unroll
        for (int ni = 0; ni < 4; ++ni)
          acc[mi][ni] = __builtin_amdgcn_mfma_f32_16x16x32_bf16(a[mi], bb[ni], acc[mi][ni], 0, 0, 0);
    }
  }

#pragma unroll
  for (int mi = 0; mi < 4; ++mi) {
    const int m_g0 = m0 + wm * 64 + mi * 16 + 4 * g;
#pragma unroll
    for (int ni = 0; ni < 4; ++ni) {
      const int n_g = n0 + wn * 64 + ni * 16 + l16;
      const float bv = bias[n_g];
      if (MODE == 0) {
        const int hh = n_g / 48, d = n_g - hh * 48;
#pragma unroll
        for (int r = 0; r < 4; ++r) {
          const int m_g = m_g0 + r;
          const int b = m_g >> 10, m = m_g & 1023;
          Oq[(((size_t)b * NH + hh) * LQ + m) * 64 + d] = f2b((acc[mi][ni][r] + bv) * QSCALE);
        }
      } else if (MODE == 2) {
#pragma unroll
        for (int r = 0; r < 4; ++r)
          Of[(size_t)(m_g0 + r) * DIMC + n_g] = acc[mi][ni][r] + bv;
      } else {
        const int b = m_g0 / LKV, s0 = m_g0 - b * LKV;
        if (n_g < DIMC) {
          const int hh = n_g / 48, d = n_g - hh * 48;
#pragma unroll
          for (int r = 0; r < 4; ++r) {
            const int s = s0 + r;
            const int dsw = (d & 7) | ((((d >> 3) ^ (s & 7)) & 7) << 3);
            Ok[(((size_t)b * NH + hh) * LKVP + s) * 64 + dsw] = f2b(acc[mi][ni][r] + bv);
          }
        } else {
          const int c = n_g - DIMC, hh = c / 48, d = c - hh * 48;
          const float* mb = (s0 < TEM)
                                ? tem + ((size_t)b * TEM + s0) * DIMC + c
                                : srch + ((size_t)b * (LKV - TEM) + (s0 - TEM)) * DIMC + c;
          const int off = s0 & 63;
          const int soff = (s0 & ~63) | ((((off >> 3) ^ d) & 7) << 3) | (off & 7);
          us4 pk;
#pragma unroll
          for (int r = 0; r < 4; ++r)
            pk[r] = f2b(acc[mi][ni][r] + bv + mb[(size_t)r * DIMC]);
          *(us4*)(Ovt + (((size_t)b * NH + hh) * 48 + d) * LKVP + soff) = pk;
        }
      }
    }
  }
}

// ---------------- flash attention: swapped QK^T, 32 q/wave, dbuf K+V ----------------
__device__ __forceinline__ void stage_tile(const char* kbase, const char* vbase, int t,
                                           char* kdst, char* vdst, int wave, int lane) {
  const char* ks = kbase + (size_t)t * 8192 + wave * 2048 + lane * 16;
  char* kd = kdst + wave * 2048;
  gload_lds16(ks, kd);
  gload_lds16(ks + 1024, kd + 1024);
  if (wave < 3) {  // V tile: 48 rows x 128B
    const char* vs = vbase + (size_t)(wave * 16 + (lane >> 3)) * (LKVP * 2) +
                     (size_t)t * 128 + (lane & 7) * 16;
    char* vd = vdst + wave * 2048;
    gload_lds16(vs, vd);
    gload_lds16(vs + 8 * (LKVP * 2), vd + 1024);
  }
}

__global__ __launch_bounds__(256, 4) void attn_fwd(
    const unsigned short* __restrict__ posb, const unsigned short* __restrict__ Qp,
    const unsigned short* __restrict__ Kp, const unsigned short* __restrict__ Vt,
    unsigned short* __restrict__ X) {
  __shared__ unsigned short Ksh[2][64 * 64];
  __shared__ unsigned short Vsh[2][48 * 64];
  __shared__ unsigned short Psh[4][16 * 64];

  const int tid = threadIdx.x;
  const int lane = tid & 63, l16 = lane & 15, g = lane >> 4;
  const int wave = tid >> 6;
  const int bid = blockIdx.x;            // xcd = bid%8 = h  (L2 locality)
  const int bh = bid & 127, qt = bid >> 7;
  const int b = bh >> 3, h = bh & 7;
  const int qrow = qt * 128 + wave * 32;

  bf16x8 qf[2][2];
#pragma unroll
  for (int qs = 0; qs < 2; ++qs) {
    const unsigned short* qb = Qp + ((size_t)bh * LQ + qrow + qs * 16 + l16) * 64 + 8 * g;
    qf[qs][0] = *(const bf16x8*)qb;
    qf[qs][1] = *(const bf16x8*)(qb + 32);
  }

  float m_run[2] = {-1e30f, -1e30f}, l_run[2] = {0.f, 0.f};
  f32x4 o[2][3];
#pragma unroll
  for (int qs = 0; qs < 2; ++qs)
#pragma unroll
    for (int d = 0; d < 3; ++d) { f32x4 z = {0.f, 0.f, 0.f, 0.f}; o[qs][d] = z; }

  const char* kbase = (const char*)(Kp + (size_t)bh * LKVP * 64);
  const char* vbase = (const char*)(Vt + (size_t)bh * 48 * LKVP);
  const int q16b = qt * 8 + wave * 2;
  const unsigned short* pq0 = posb + (((size_t)h * 64 + q16b) * NKVT) * 1024 + lane * 16;
  const unsigned short* pq1 = pq0 + (size_t)NKVT * 1024;
  char* pbase = (char*)&Psh[wave][0] + l16 * 128;
  const int swz = (l16 & 7) << 4;

  stage_tile(kbase, vbase, 0, (char*)&Ksh[0][0], (char*)&Vsh[0][0], wave, lane);
  asm volatile("s_waitcnt vmcnt(0)" ::: "memory");
  __syncthreads();

  int buf = 0;
  for (int t = 0; t < NKVT; ++t) {
    if (t + 1 < NKVT)
      stage_tile(kbase, vbase, t + 1, (char*)&Ksh[buf ^ 1][0], (char*)&Vsh[buf ^ 1][0],
                 wave, lane);

    // pos loads (L2-resident; issue early, consumed after QK)
    bf16x8 pA0 = *(const bf16x8*)(pq0);
    bf16x8 pA1 = *(const bf16x8*)(pq0 + 8);
    bf16x8 pB0 = *(const bf16x8*)(pq1);
    bf16x8 pB1 = *(const bf16x8*)(pq1 + 8);
    pq0 += 1024; pq1 += 1024;

    // QK^T swapped: s[qs][ni] holds S^T (q = l16, k = 16*ni + 4g + r)
    f32x4 s[2][4];
#pragma unroll
    for (int qs = 0; qs < 2; ++qs)
#pragma unroll
      for (int ni = 0; ni < 4; ++ni) { f32x4 z = {0.f, 0.f, 0.f, 0.f}; s[qs][ni] = z; }
#pragma unroll
    for (int ni = 0; ni < 4; ++ni) {
      const int krow = ni * 16 + l16;
      const char* kr = (const char*)&Ksh[buf][0] + krow * 128;
      bf16x8 kf0 = *(const bf16x8*)(kr + ((g ^ (krow & 7)) << 4));
      bf16x8 kf1 = *(const bf16x8*)(kr + (((g + 4) ^ (krow & 7)) << 4));
      s[0][ni] = __builtin_amdgcn_mfma_f32_16x16x32_bf16(kf0, qf[0][0], s[0][ni], 0, 0, 0);
      s[0][ni] = __builtin_amdgcn_mfma_f32_16x16x32_bf16(kf1, qf[0][1], s[0][ni], 0, 0, 0);
      s[1][ni] = __builtin_amdgcn_mfma_f32_16x16x32_bf16(kf0, qf[1][0], s[1][ni], 0, 0, 0);
      s[1][ni] = __builtin_amdgcn_mfma_f32_16x16x32_bf16(kf1, qf[1][1], s[1][ni], 0, 0, 0);
    }

    // per-qset: lane-local softmax row (defer-max THR=8), pack P, PV fragments
    bf16x8 af[2][2];
#pragma unroll
    for (int qs = 0; qs < 2; ++qs) {
      float x[16];
#pragma unroll
      for (int ni = 0; ni < 4; ++ni)
#pragma unroll
        for (int r = 0; r < 4; ++r) {
          const int idx = ni * 4 + r;
          unsigned short u =
              (unsigned short)(qs == 0 ? (idx < 8 ? pA0[idx] : pA1[idx - 8])
                                       : (idx < 8 ? pB0[idx] : pB1[idx - 8]));
          x[idx] = s[qs][ni][r] + b2f(u);
        }
      float mx = x[0];
#pragma unroll
      for (int i = 1; i < 16; ++i) mx = fmaxf(mx, x[i]);
      mx = fmaxf(mx, __shfl_xor(mx, 16));
      mx = fmaxf(mx, __shfl_xor(mx, 32));
      if (__any(mx > m_run[qs] + 8.f)) {  // rescale path (rare)
        const float mn = fmaxf(m_run[qs], mx);
        const float al = exp2f(m_run[qs] - mn);
        m_run[qs] = mn;
        l_run[qs] *= al;
#pragma unroll
        for (int r = 0; r < 4; ++r) {
          const float ab = __shfl(al, 4 * (lane >> 4) + r);
          o[qs][0][r] *= ab; o[qs][1][r] *= ab; o[qs][2][r] *= ab;
        }
      }
      const float base = m_run[qs];
      float sum = 0.f;
#pragma unroll
      for (int i = 0; i < 16; ++i) { x[i] = exp2f(x[i] - base); sum += x[i]; }
      sum += __shfl_xor(sum, 16);
      sum += __shfl_xor(sum, 32);
      l_run[qs] += sum;

      // pack 4 bf16 per ni, swizzled ds_write_b64; then read A-fragments
#pragma unroll
      for (int ni = 0; ni < 4; ++ni) {
        unsigned int lo, hi;
        asm("v_cvt_pk_bf16_f32 %0, %1, %2" : "=v"(lo) : "v"(x[4 * ni]), "v"(x[4 * ni + 1]));
        asm("v_cvt_pk_bf16_f32 %0, %1, %2" : "=v"(hi) : "v"(x[4 * ni + 2]), "v"(x[4 * ni + 3]));
        u32x2 pk = {lo, hi};
        *(u32x2*)(pbase + ((32 * ni + 8 * g) ^ swz)) = pk;
      }
      af[qs][0] = *(const bf16x8*)(pbase + ((16 * g) ^ swz));
      af[qs][1] = *(const bf16x8*)(pbase + ((64 + 16 * g) ^ swz));
    }

    // PV: o[qs] += P * V   (vf shared between qsets)
#pragma unroll
    for (int dn = 0; dn < 3; ++dn) {
      const int vr = 16 * dn + l16;
      const char* vrp = (const char*)&Vsh[buf][0] + vr * 128;
      bf16x8 vf0 = *(const bf16x8*)(vrp + ((g ^ (vr & 7)) << 4));
      bf16x8 vf1 = *(const bf16x8*)(vrp + (((g + 4) ^ (vr & 7)) << 4));
      o[0][dn] = __builtin_amdgcn_mfma_f32_16x16x32_bf16(af[0][0], vf0, o[0][dn], 0, 0, 0);
      o[0][dn] = __builtin_amdgcn_mfma_f32_16x16x32_bf16(af[0][1], vf1, o[0][dn], 0, 0, 0);
      o[1][dn] = __builtin_amdgcn_mfma_f32_16x16x32_bf16(af[1][0], vf0, o[1][dn], 0, 0, 0);
      o[1][dn] = __builtin_amdgcn_mfma_f32_16x16x32_bf16(af[1][1], vf1, o[1][dn], 0, 0, 0);
    }

    asm volatile("s_waitcnt vmcnt(0)" ::: "memory");
    __syncthreads();
    buf ^= 1;
  }

  // epilogue: broadcast 1/l per o-row, write X pre-swizzled for out-proj
#pragma unroll
  for (int qs = 0; qs < 2; ++qs) {
    const float linv = 1.f / l_run[qs];
#pragma unroll
    for (int r = 0; r < 4; ++r) {
      const float ib = __shfl(linv, 4 * (lane >> 4) + r);
      const int m = qrow + qs * 16 + 4 * g + r;
#pragma unroll
      for (int dn = 0; dn < 3; ++dn) {
        const int c = h * 48 + 16 * dn + l16;
        const int cs = (c & ~63) | (c & 7) | ((((c >> 3) & 7) ^ (m & 7)) << 3);
        X[((size_t)b * LQ + m) * DIMC + cs] = f2b(o[qs][dn][r] * ib);
      }
    }
  }
}

// ---------------- launch ----------------
extern "C" void kernel_launch(void* const* d_in, const int* in_sizes, int n_in,
                              void* d_out, int out_size, void* d_ws, size_t ws_size,
                              hipStream_t stream) {
  const float* tem  = (const float*)d_in[0];
  const float* srch = (const float*)d_in[1];
  const float* q    = (const float*)d_in[2];
  const float* kv   = (const float*)d_in[3];
  const float* pos  = (const float*)d_in[4];
  const float* q_w  = (const float*)d_in[5];
  const float* q_b  = (const float*)d_in[6];
  const float* kv_w = (const float*)d_in[7];
  const float* kv_b = (const float*)d_in[8];
  const float* p_w  = (const float*)d_in[9];
  const float* p_b  = (const float*)d_in[10];
  float* out = (float*)d_out;

  char* w = (char*)d_ws;
  unsigned short* Qp   = (unsigned short*)(w);              // 16.8 MB (b,h,Lq,64)
  unsigned short* Kp   = (unsigned short*)(w + 16777216);   // 24.1 MB (b,h,LKVP,64) swz
  unsigned short* Vt   = (unsigned short*)(w + 40894464);   // 18.1 MB (b,h,48,LKVP) swz
  unsigned short* X    = (unsigned short*)(w + 58982400);   // 12.6 MB (B*LQ,384) swz — aliases qb
  unsigned short* qb   = X;                                 //   (dead before attn writes X)
  unsigned short* posb = (unsigned short*)(w + 71565312);   // 24.1 MB fragment-ordered pos
  unsigned short* kvb  = (unsigned short*)(w + 95682560);   // 17.5 MB
  unsigned short* qwb  = (unsigned short*)(w + 113180672);  // 0.3 MB
  unsigned short* kvwb = (unsigned short*)(w + 113475584);  // 0.6 MB
  unsigned short* pwb  = (unsigned short*)(w + 114065408);  // 0.3 MB

  conv_swz<<<3072, 256, 0, stream>>>(q, qb, 16384 * 48);
  conv_swz<<<4272, 256, 0, stream>>>(kv, kvb, 22784 * 48);
  conv_swz<<<72, 256, 0, stream>>>(q_w, qwb, 384 * 48);
  conv_swz<<<144, 256, 0, stream>>>(kv_w, kvwb, 768 * 48);
  conv_swz<<<72, 256, 0, stream>>>(p_w, pwb, 384 * 48);
  zero_qpad<<<512, 256, 0, stream>>>(Qp);
  zero_kpad<<<736, 256, 0, stream>>>(Kp);
  zero_vpad<<<144, 256, 0, stream>>>(Vt);
  prep_pos<<<dim3(NKVT, 16, NH), 256, 0, stream>>>(pos, posb);
  proj_gemm<0><<<dim3(3, 128), 256, 0, stream>>>(qb, qwb, q_b, nullptr, nullptr,
                                                 Qp, nullptr, nullptr, nullptr);
  proj_gemm<1><<<dim3(6, 178), 256, 0, stream>>>(kvb, kvwb, kv_b, tem, srch,
                                                 nullptr, Kp, Vt, nullptr);
  attn_fwd<<<1024, 256, 0, stream>>>(posb, Qp, Kp, Vt, X);
  proj_gemm<2><<<dim3(3, 128), 256, 0, stream>>>(X, pwb, p_b, nullptr, nullptr,
                                                 nullptr, nullptr, nullptr, out);
}

// Round 5
// 214.357 us; speedup vs baseline: 1.6209x; 1.0868x over previous
//
#include <hip/hip_runtime.h>
#include <stdint.h>

#define NB 16
#define NH 8
#define LQ 1024
#define LKV 1424
#define LKVP 1472
#define DIMC 384
#define NKVT 23
#define TEM 400
#define QSCALE 0.20823509f       // (1/sqrt(48)) * log2(e)
#define LOG2E_F 1.4426950408889634f

typedef __attribute__((ext_vector_type(4))) float f32x4;
typedef __attribute__((ext_vector_type(8))) short bf16x8;
typedef __attribute__((ext_vector_type(4))) unsigned short us4;
typedef __attribute__((ext_vector_type(2))) unsigned int u32x2;
typedef __attribute__((ext_vector_type(4))) unsigned int u32x4;

__device__ __forceinline__ unsigned short f2b(float f) {
  unsigned int u = __builtin_bit_cast(unsigned int, f);
  u += 0x7fffu + ((u >> 16) & 1u);  // round-to-nearest-even
  return (unsigned short)(u >> 16);
}

__device__ __forceinline__ void gload_lds16(const void* gsrc, void* ldst) {
  __builtin_amdgcn_global_load_lds(
      (const __attribute__((address_space(1))) void*)gsrc,
      (__attribute__((address_space(3))) void*)ldst, 16, 0, 0);
}

// ---------- fused convert: 5 f32 [R][384] tensors -> bf16 pre-swizzled ----------
__global__ __launch_bounds__(256) void conv_all(
    const float* __restrict__ q, const float* __restrict__ kv,
    const float* __restrict__ qw, const float* __restrict__ kvw,
    const float* __restrict__ pw, unsigned short* __restrict__ qb,
    unsigned short* __restrict__ kvb, unsigned short* __restrict__ qwb,
    unsigned short* __restrict__ kvwb, unsigned short* __restrict__ pwb) {
  int i = blockIdx.x * 256 + threadIdx.x;
  const float* src;
  unsigned short* dst;
  if (i < 16384 * 48) { src = q; dst = qb; }
  else if (i < 39168 * 48) { i -= 16384 * 48; src = kv; dst = kvb; }
  else if (i < 39552 * 48) { i -= 39168 * 48; src = qw; dst = qwb; }
  else if (i < 40320 * 48) { i -= 39552 * 48; src = kvw; dst = kvwb; }
  else if (i < 40704 * 48) { i -= 40320 * 48; src = pw; dst = pwb; }
  else return;
  int row = i / 48, ch = i - row * 48;
  const float* sp = src + (size_t)row * DIMC + ch * 8;
  f32x4 x = *(const f32x4*)sp;
  f32x4 y = *(const f32x4*)(sp + 4);
  bf16x8 o;
  o[0] = (short)f2b(x[0]); o[1] = (short)f2b(x[1]);
  o[2] = (short)f2b(x[2]); o[3] = (short)f2b(x[3]);
  o[4] = (short)f2b(y[0]); o[5] = (short)f2b(y[1]);
  o[6] = (short)f2b(y[2]); o[7] = (short)f2b(y[3]);
  int blk = ch >> 3, c3 = (ch & 7) ^ (row & 7);
  *(bf16x8*)(dst + (size_t)row * DIMC + blk * 64 + c3 * 8) = o;
}

// ---------- fused exact pad zeroing ----------
__global__ __launch_bounds__(256) void zero_pads(unsigned short* Qp, unsigned short* Kp,
                                                 unsigned short* Vt) {
  int i = blockIdx.x * 256 + threadIdx.x;
  u32x4 z = {0u, 0u, 0u, 0u};
  if (i < 131072) {
    *(u32x4*)(Qp + (size_t)i * 64 + 48) = z;
    *(u32x4*)(Qp + (size_t)i * 64 + 56) = z;
  } else if (i < 131072 + 188416) {
    int r = i - 131072;
    int s = r % LKVP;
    unsigned short* row = Kp + (size_t)r * 64;
    if (s < LKV) {
      *(u32x4*)(row + (6 ^ (s & 7)) * 8) = z;
      *(u32x4*)(row + (7 ^ (s & 7)) * 8) = z;
    } else {
#pragma unroll
      for (int c = 0; c < 64; c += 8) *(u32x4*)(row + c) = z;
    }
  } else if (i < 131072 + 188416 + 36864) {
    int j = i - 319488;
    int row = j / 6, x = 2 + j - (j / 6) * 6;
    int d = row % 48;
    *(u32x4*)(Vt + (size_t)row * LKVP + 1408 + ((x ^ d) & 7) * 8) = z;
  }
}

// ---------- pos prep v2: coalesced reads, LDS transpose, bf16 fragment order ----------
// posb[((h*64+q16)*23+t)*64+lane]*16 + (4ni+r) = pos[h][q16*16+l16][t*64+16ni+4g+r]*log2e
__global__ __launch_bounds__(256) void prep_pos(const float* __restrict__ pos,
                                                unsigned short* __restrict__ posb) {
  __shared__ float lds[4][1024];
  const int wave = threadIdx.x >> 6, lane = threadIdx.x & 63;
  const int l16 = lane & 15, g = lane >> 4;
  const int q16 = blockIdx.x, h = blockIdx.y;
  float* L = &lds[wave][0];

  for (int t = wave; t < NKVT; t += 4) {
#pragma unroll
    for (int i = 0; i < 4; ++i) {
      const int row = i * 4 + g;
      const int gcol = t * 64 + l16 * 4;
      f32x4 v;
      if (gcol < LKV) {
        v = *(const f32x4*)(pos + ((size_t)h * LQ + q16 * 16 + row) * LKV + gcol);
        v *= LOG2E_F;
      } else {
        f32x4 neg = {-1e30f, -1e30f, -1e30f, -1e30f};
        v = neg;
      }
      *(f32x4*)(L + row * 64 + ((l16 ^ (row & 7)) << 2)) = v;
    }
    unsigned short vals[16];
#pragma unroll
    for (int ni = 0; ni < 4; ++ni) {
      f32x4 wv = *(const f32x4*)(L + l16 * 64 + (((4 * ni + g) ^ (l16 & 7)) << 2));
#pragma unroll
      for (int r = 0; r < 4; ++r) vals[4 * ni + r] = f2b(wv[r]);
    }
    unsigned short* op = posb + ((((size_t)h * 64 + q16) * NKVT + t) * 64 + lane) * 16;
    bf16x8 a, b;
#pragma unroll
    for (int k = 0; k < 8; ++k) { a[k] = (short)vals[k]; b[k] = (short)vals[8 + k]; }
    *(bf16x8*)op = a;
    *(bf16x8*)(op + 8) = b;
  }
}

// ---------- projection GEMMs: 128x128 tile, BK=64, gload_lds staging ----------
template <int MODE>
__global__ __launch_bounds__(256) void proj_gemm(
    const unsigned short* __restrict__ A, const unsigned short* __restrict__ Wb,
    const float* __restrict__ bias, const float* __restrict__ tem,
    const float* __restrict__ srch, unsigned short* __restrict__ Oq,
    unsigned short* __restrict__ Ok, unsigned short* __restrict__ Ovt,
    float* __restrict__ Of) {
  __shared__ unsigned short Ash[128 * 64];
  __shared__ unsigned short Bsh[128 * 64];
  const int tid = threadIdx.x;
  const int lane = tid & 63, l16 = lane & 15, g = lane >> 4;
  const int wave = tid >> 6, wm = wave >> 1, wn = wave & 1;
  const int n0 = blockIdx.x * 128, m0 = blockIdx.y * 128;

  f32x4 acc[4][4];
#pragma unroll
  for (int i = 0; i < 4; ++i)
#pragma unroll
    for (int j = 0; j < 4; ++j) { f32x4 z = {0.f, 0.f, 0.f, 0.f}; acc[i][j] = z; }

  const char* Abase = (const char*)A + (size_t)m0 * 768;
  const char* Bbase = (const char*)Wb + (size_t)n0 * 768;

  for (int ks = 0; ks < 6; ++ks) {
    __syncthreads();
#pragma unroll
    for (int rnd = 0; rnd < 4; ++rnd) {
      int idx = tid + rnd * 256;
      int row = idx >> 3, chunk = idx & 7;
      gload_lds16(Abase + (size_t)row * 768 + ks * 128 + chunk * 16,
                  (char*)Ash + idx * 16);
    }
#pragma unroll
    for (int rnd = 0; rnd < 4; ++rnd) {
      int idx = tid + rnd * 256;
      int row = idx >> 3, chunk = idx & 7;
      gload_lds16(Bbase + (size_t)row * 768 + ks * 128 + chunk * 16,
                  (char*)Bsh + idx * 16);
    }
    asm volatile("s_waitcnt vmcnt(0)" ::: "memory");
    __syncthreads();
#pragma unroll
    for (int kk = 0; kk < 2; ++kk) {
      bf16x8 a[4], bb[4];
#pragma unroll
      for (int mi = 0; mi < 4; ++mi) {
        int row = wm * 64 + mi * 16 + l16;
        a[mi] = *(const bf16x8*)((char*)Ash + row * 128 + (((g + 4 * kk) ^ (row & 7)) << 4));
      }
#pragma unroll
      for (int ni = 0; ni < 4; ++ni) {
        int row = wn * 64 + ni * 16 + l16;
        bb[ni] = *(const bf16x8*)((char*)Bsh + row * 128 + (((g + 4 * kk) ^ (row & 7)) << 4));
      }
#pragma unroll
      for (int mi = 0; mi < 4; ++mi)
#pragma unroll
        for (int ni = 0; ni < 4; ++ni)
          acc[mi][ni] = __builtin_amdgcn_mfma_f32_16x16x32_bf16(a[mi], bb[ni], acc[mi][ni], 0, 0, 0);
    }
  }

#pragma unroll
  for (int mi = 0; mi < 4; ++mi) {
    const int m_g0 = m0 + wm * 64 + mi * 16 + 4 * g;
#pragma unroll
    for (int ni = 0; ni < 4; ++ni) {
      const int n_g = n0 + wn * 64 + ni * 16 + l16;
      const float bv = bias[n_g];
      if (MODE == 0) {
        const int hh = n_g / 48, d = n_g - hh * 48;
#pragma unroll
        for (int r = 0; r < 4; ++r) {
          const int m_g = m_g0 + r;
          const int b = m_g >> 10, m = m_g & 1023;
          Oq[(((size_t)b * NH + hh) * LQ + m) * 64 + d] = f2b((acc[mi][ni][r] + bv) * QSCALE);
        }
      } else if (MODE == 2) {
#pragma unroll
        for (int r = 0; r < 4; ++r)
          Of[(size_t)(m_g0 + r) * DIMC + n_g] = acc[mi][ni][r] + bv;
      } else {
        const int b = m_g0 / LKV, s0 = m_g0 - b * LKV;
        if (n_g < DIMC) {
          const int hh = n_g / 48, d = n_g - hh * 48;
#pragma unroll
          for (int r = 0; r < 4; ++r) {
            const int s = s0 + r;
            const int dsw = (d & 7) | ((((d >> 3) ^ (s & 7)) & 7) << 3);
            Ok[(((size_t)b * NH + hh) * LKVP + s) * 64 + dsw] = f2b(acc[mi][ni][r] + bv);
          }
        } else {
          const int c = n_g - DIMC, hh = c / 48, d = c - hh * 48;
          const float* mb = (s0 < TEM)
                                ? tem + ((size_t)b * TEM + s0) * DIMC + c
                                : srch + ((size_t)b * (LKV - TEM) + (s0 - TEM)) * DIMC + c;
          const int off = s0 & 63;
          const int soff = (s0 & ~63) | ((((off >> 3) ^ d) & 7) << 3) | (off & 7);
          us4 pk;
#pragma unroll
          for (int r = 0; r < 4; ++r)
            pk[r] = f2b(acc[mi][ni][r] + bv + mb[(size_t)r * DIMC]);
          *(us4*)(Ovt + (((size_t)b * NH + hh) * 48 + d) * LKVP + soff) = pk;
        }
      }
    }
  }
}

// ---------------- flash attention ----------------
__device__ __forceinline__ void stage_tile(const char* kbase, const char* vbase, int t,
                                           char* kdst, char* vdst, int wave, int lane) {
  const char* ks = kbase + (size_t)t * 8192 + wave * 2048 + lane * 16;
  char* kd = kdst + wave * 2048;
  gload_lds16(ks, kd);
  gload_lds16(ks + 1024, kd + 1024);
  if (wave < 3) {
    const char* vs = vbase + (size_t)(wave * 16 + (lane >> 3)) * (LKVP * 2) +
                     (size_t)t * 128 + (lane & 7) * 16;
    char* vd = vdst + wave * 2048;
    gload_lds16(vs, vd);
    gload_lds16(vs + 8 * (LKVP * 2), vd + 1024);
  }
}

// lane-local softmax over 16 k-values held in sx (q = lane&15); defer-max THR=8
__device__ __forceinline__ void softmax16(f32x4 (&sx)[4], float& m_run, float& l_run,
                                          f32x4& o0, f32x4& o1, f32x4& o2, int lane) {
  float a0 = fmaxf(fmaxf(sx[0][0], sx[0][1]), sx[0][2]);
  float a1 = fmaxf(fmaxf(sx[0][3], sx[1][0]), sx[1][1]);
  float a2 = fmaxf(fmaxf(sx[1][2], sx[1][3]), sx[2][0]);
  float a3 = fmaxf(fmaxf(sx[2][1], sx[2][2]), sx[2][3]);
  float a4 = fmaxf(fmaxf(sx[3][0], sx[3][1]), sx[3][2]);
  float mx = fmaxf(fmaxf(fmaxf(a0, a1), fmaxf(a2, a3)), fmaxf(a4, sx[3][3]));
  mx = fmaxf(mx, __shfl_xor(mx, 16));
  mx = fmaxf(mx, __shfl_xor(mx, 32));
  if (__any(mx > m_run + 8.f)) {
    const float mn = fmaxf(m_run, mx);
    const float al = exp2f(m_run - mn);
    m_run = mn;
    l_run *= al;
#pragma unroll
    for (int r = 0; r < 4; ++r) {
      const float ab = __shfl(al, 4 * (lane >> 4) + r);
      o0[r] *= ab; o1[r] *= ab; o2[r] *= ab;
    }
  }
  const float base = m_run;
#pragma unroll
  for (int ni = 0; ni < 4; ++ni)
#pragma unroll
    for (int r = 0; r < 4; ++r) sx[ni][r] = exp2f(sx[ni][r] - base);
  float s0 = (sx[0][0] + sx[0][1]) + (sx[0][2] + sx[0][3]);
  float s1 = (sx[1][0] + sx[1][1]) + (sx[1][2] + sx[1][3]);
  float s2 = (sx[2][0] + sx[2][1]) + (sx[2][2] + sx[2][3]);
  float s3 = (sx[3][0] + sx[3][1]) + (sx[3][2] + sx[3][3]);
  float sum = (s0 + s1) + (s2 + s3);
  sum += __shfl_xor(sum, 16);
  sum += __shfl_xor(sum, 32);
  l_run += sum;
}

// pack P (exp values) to bf16 via per-wave swizzled LDS; return PV A-fragments
__device__ __forceinline__ void packP(const f32x4 (&sx)[4], char* pbase, int swz, int g,
                                      bf16x8& af0, bf16x8& af1) {
#pragma unroll
  for (int ni = 0; ni < 4; ++ni) {
    float e0 = sx[ni][0], e1 = sx[ni][1], e2 = sx[ni][2], e3 = sx[ni][3];
    unsigned int lo, hi;
    asm("v_cvt_pk_bf16_f32 %0, %1, %2" : "=v"(lo) : "v"(e0), "v"(e1));
    asm("v_cvt_pk_bf16_f32 %0, %1, %2" : "=v"(hi) : "v"(e2), "v"(e3));
    u32x2 pk = {lo, hi};
    *(u32x2*)(pbase + ((32 * ni + 8 * g) ^ swz)) = pk;
  }
  af0 = *(const bf16x8*)(pbase + ((16 * g) ^ swz));
  af1 = *(const bf16x8*)(pbase + ((64 + 16 * g) ^ swz));
}

__global__ __launch_bounds__(256, 4) void attn_fwd(
    const unsigned short* __restrict__ posb, const unsigned short* __restrict__ Qp,
    const unsigned short* __restrict__ Kp, const unsigned short* __restrict__ Vt,
    unsigned short* __restrict__ X) {
  __shared__ unsigned short Ksh[2][64 * 64];
  __shared__ unsigned short Vsh[2][48 * 64];
  __shared__ unsigned short Psh[4][16 * 64];

  const int tid = threadIdx.x;
  const int lane = tid & 63, l16 = lane & 15, g = lane >> 4;
  const int wave = tid >> 6;
  const int bid = blockIdx.x;  // xcd = bid%8 = h (L2 locality)
  const int bh = bid & 127, qt = bid >> 7;
  const int b = bh >> 3, h = bh & 7;
  const int qrow = qt * 128 + wave * 32;

  bf16x8 qf[2][2];
#pragma unroll
  for (int qs = 0; qs < 2; ++qs) {
    const unsigned short* qb = Qp + ((size_t)bh * LQ + qrow + qs * 16 + l16) * 64 + 8 * g;
    qf[qs][0] = *(const bf16x8*)qb;
    qf[qs][1] = *(const bf16x8*)(qb + 32);
  }

  float m_run0 = -1e30f, m_run1 = -1e30f, l_run0 = 0.f, l_run1 = 0.f;
  f32x4 o[2][3];
#pragma unroll
  for (int qs = 0; qs < 2; ++qs)
#pragma unroll
    for (int d = 0; d < 3; ++d) { f32x4 z = {0.f, 0.f, 0.f, 0.f}; o[qs][d] = z; }

  const char* kbase = (const char*)(Kp + (size_t)bh * LKVP * 64);
  const char* vbase = (const char*)(Vt + (size_t)bh * 48 * LKVP);
  const int q16b = qt * 8 + wave * 2;
  const unsigned short* pq0 = posb + (((size_t)h * 64 + q16b) * NKVT) * 1024 + lane * 16;
  const unsigned short* pq1 = pq0 + (size_t)NKVT * 1024;
  char* pbase = (char*)&Psh[wave][0] + l16 * 128;
  const int swz = (l16 & 7) << 4;

  stage_tile(kbase, vbase, 0, (char*)&Ksh[0][0], (char*)&Vsh[0][0], wave, lane);
  asm volatile("s_waitcnt vmcnt(0)" ::: "memory");
  __syncthreads();

  int buf = 0;
  for (int t = 0; t < NKVT; ++t) {
    if (t + 1 < NKVT)
      stage_tile(kbase, vbase, t + 1, (char*)&Ksh[buf ^ 1][0], (char*)&Vsh[buf ^ 1][0],
                 wave, lane);

    // pos tile -> QK accumulator init (1 VALU op per value)
    u32x4 w0 = *(const u32x4*)(pq0);
    u32x4 w1 = *(const u32x4*)(pq0 + 8);
    u32x4 w2 = *(const u32x4*)(pq1);
    u32x4 w3 = *(const u32x4*)(pq1 + 8);
    pq0 += 1024; pq1 += 1024;

    f32x4 s0[4], s1[4];
#pragma unroll
    for (int k = 0; k < 4; ++k) {
      const int ni = k >> 1, j2 = (k & 1) * 2;
      unsigned int a = w0[k], bb_ = w1[k], c = w2[k], d = w3[k];
      s0[ni][j2]     = __builtin_bit_cast(float, a << 16);
      s0[ni][j2 + 1] = __builtin_bit_cast(float, a & 0xffff0000u);
      s0[ni + 2][j2]     = __builtin_bit_cast(float, bb_ << 16);
      s0[ni + 2][j2 + 1] = __builtin_bit_cast(float, bb_ & 0xffff0000u);
      s1[ni][j2]     = __builtin_bit_cast(float, c << 16);
      s1[ni][j2 + 1] = __builtin_bit_cast(float, c & 0xffff0000u);
      s1[ni + 2][j2]     = __builtin_bit_cast(float, d << 16);
      s1[ni + 2][j2 + 1] = __builtin_bit_cast(float, d & 0xffff0000u);
    }

    // QK^T swapped (q = l16 lane-local)
#pragma unroll
    for (int ni = 0; ni < 4; ++ni) {
      const int krow = ni * 16 + l16;
      const char* kr = (const char*)&Ksh[buf][0] + krow * 128;
      bf16x8 kf0 = *(const bf16x8*)(kr + ((g ^ (krow & 7)) << 4));
      bf16x8 kf1 = *(const bf16x8*)(kr + (((g + 4) ^ (krow & 7)) << 4));
      s0[ni] = __builtin_amdgcn_mfma_f32_16x16x32_bf16(kf0, qf[0][0], s0[ni], 0, 0, 0);
      s0[ni] = __builtin_amdgcn_mfma_f32_16x16x32_bf16(kf1, qf[0][1], s0[ni], 0, 0, 0);
      s1[ni] = __builtin_amdgcn_mfma_f32_16x16x32_bf16(kf0, qf[1][0], s1[ni], 0, 0, 0);
      s1[ni] = __builtin_amdgcn_mfma_f32_16x16x32_bf16(kf1, qf[1][1], s1[ni], 0, 0, 0);
    }

    // SM0 -> pack0(+af0 loads) -> SM1 (hides af0 latency) -> PV0 (MFMA pipe
    // overlaps pack1) -> pack1 -> PV1
    softmax16(s0, m_run0, l_run0, o[0][0], o[0][1], o[0][2], lane);
    bf16x8 af00, af01, af10, af11;
    packP(s0, pbase, swz, g, af00, af01);
    softmax16(s1, m_run1, l_run1, o[1][0], o[1][1], o[1][2], lane);
#pragma unroll
    for (int dn = 0; dn < 3; ++dn) {
      const int vr = 16 * dn + l16;
      const char* vrp = (const char*)&Vsh[buf][0] + vr * 128;
      bf16x8 vf0 = *(const bf16x8*)(vrp + ((g ^ (vr & 7)) << 4));
      bf16x8 vf1 = *(const bf16x8*)(vrp + (((g + 4) ^ (vr & 7)) << 4));
      o[0][dn] = __builtin_amdgcn_mfma_f32_16x16x32_bf16(af00, vf0, o[0][dn], 0, 0, 0);
      o[0][dn] = __builtin_amdgcn_mfma_f32_16x16x32_bf16(af01, vf1, o[0][dn], 0, 0, 0);
    }
    packP(s1, pbase, swz, g, af10, af11);
#pragma unroll
    for (int dn = 0; dn < 3; ++dn) {
      const int vr = 16 * dn + l16;
      const char* vrp = (const char*)&Vsh[buf][0] + vr * 128;
      bf16x8 vf0 = *(const bf16x8*)(vrp + ((g ^ (vr & 7)) << 4));
      bf16x8 vf1 = *(const bf16x8*)(vrp + (((g + 4) ^ (vr & 7)) << 4));
      o[1][dn] = __builtin_amdgcn_mfma_f32_16x16x32_bf16(af10, vf0, o[1][dn], 0, 0, 0);
      o[1][dn] = __builtin_amdgcn_mfma_f32_16x16x32_bf16(af11, vf1, o[1][dn], 0, 0, 0);
    }

    asm volatile("s_waitcnt vmcnt(0)" ::: "memory");
    __syncthreads();
    buf ^= 1;
  }

  // epilogue: broadcast 1/l per o-row, write X pre-swizzled for out-proj
#pragma unroll
  for (int qs = 0; qs < 2; ++qs) {
    const float linv = 1.f / (qs == 0 ? l_run0 : l_run1);
#pragma unroll
    for (int r = 0; r < 4; ++r) {
      const float ib = __shfl(linv, 4 * (lane >> 4) + r);
      const int m = qrow + qs * 16 + 4 * g + r;
#pragma unroll
      for (int dn = 0; dn < 3; ++dn) {
        const int c = h * 48 + 16 * dn + l16;
        const int cs = (c & ~63) | (c & 7) | ((((c >> 3) & 7) ^ (m & 7)) << 3);
        X[((size_t)b * LQ + m) * DIMC + cs] = f2b(o[qs][dn][r] * ib);
      }
    }
  }
}

// ---------------- launch ----------------
extern "C" void kernel_launch(void* const* d_in, const int* in_sizes, int n_in,
                              void* d_out, int out_size, void* d_ws, size_t ws_size,
                              hipStream_t stream) {
  const float* tem  = (const float*)d_in[0];
  const float* srch = (const float*)d_in[1];
  const float* q    = (const float*)d_in[2];
  const float* kv   = (const float*)d_in[3];
  const float* pos  = (const float*)d_in[4];
  const float* q_w  = (const float*)d_in[5];
  const float* q_b  = (const float*)d_in[6];
  const float* kv_w = (const float*)d_in[7];
  const float* kv_b = (const float*)d_in[8];
  const float* p_w  = (const float*)d_in[9];
  const float* p_b  = (const float*)d_in[10];
  float* out = (float*)d_out;

  char* w = (char*)d_ws;
  unsigned short* Qp   = (unsigned short*)(w);              // 16.8 MB (b,h,Lq,64)
  unsigned short* Kp   = (unsigned short*)(w + 16777216);   // 24.1 MB (b,h,LKVP,64) swz
  unsigned short* Vt   = (unsigned short*)(w + 40894464);   // 18.1 MB (b,h,48,LKVP) swz
  unsigned short* X    = (unsigned short*)(w + 58982400);   // 12.6 MB (B*LQ,384) swz — aliases qb
  unsigned short* qb   = X;                                 //   (dead before attn writes X)
  unsigned short* posb = (unsigned short*)(w + 71565312);   // 24.1 MB fragment-ordered pos
  unsigned short* kvb  = (unsigned short*)(w + 95682560);   // 17.5 MB
  unsigned short* qwb  = (unsigned short*)(w + 113180672);  // 0.3 MB
  unsigned short* kvwb = (unsigned short*)(w + 113475584);  // 0.6 MB
  unsigned short* pwb  = (unsigned short*)(w + 114065408);  // 0.3 MB

  conv_all<<<7632, 256, 0, stream>>>(q, kv, q_w, kv_w, p_w, qb, kvb, qwb, kvwb, pwb);
  zero_pads<<<1392, 256, 0, stream>>>(Qp, Kp, Vt);
  prep_pos<<<dim3(64, 8), 256, 0, stream>>>(pos, posb);
  proj_gemm<0><<<dim3(3, 128), 256, 0, stream>>>(qb, qwb, q_b, nullptr, nullptr,
                                                 Qp, nullptr, nullptr, nullptr);
  proj_gemm<1><<<dim3(6, 178), 256, 0, stream>>>(kvb, kvwb, kv_b, tem, srch,
                                                 nullptr, Kp, Vt, nullptr);
  attn_fwd<<<1024, 256, 0, stream>>>(posb, Qp, Kp, Vt, X);
  proj_gemm<2><<<dim3(3, 128), 256, 0, stream>>>(X, pwb, p_b, nullptr, nullptr,
                                                 nullptr, nullptr, nullptr, out);
}